// Round 8
// baseline (1606.747 us; speedup 1.0000x reference)
//
#include <hip/hip_runtime.h>
#include <hip/hip_bf16.h>
#include <cstdint>
#include <cstddef>

#define N_G 50000
#define N_D 20000
#define E_G 300000
#define E_D 150000
#define BATCH 65536

typedef _Float16 f16;
typedef _Float16 f16x8 __attribute__((ext_vector_type(8)));
typedef _Float16 f16x4 __attribute__((ext_vector_type(4)));
typedef float f32x4 __attribute__((ext_vector_type(4)));

__device__ __forceinline__ float clampf(float v) {
    return fminf(fmaxf(v, -60000.f), 60000.f);  // also squashes NaN
}

__device__ __forceinline__ void gl_lds16(const void* g, void* l) {
    __builtin_amdgcn_global_load_lds(
        (const __attribute__((address_space(1))) unsigned int*)g,
        (__attribute__((address_space(3))) unsigned int*)l, 16, 0, 0);
}

// ---------------- GEMM (128x128, 4 waves): C = act(A @ Bt^T + bias) ----------------
// R15: this is the exact R9-round source (84 VGPR / 28% occupancy proven form).
// Head only: lin1 (gather), lin2 (plain), lin3 (+fused lin4 via W4/outF).
// NO stats/c2/deg anywhere in this body — R13 showed extra epilogue params cost
// 84->96 VGPR on every caller. Tower variant is a separate copy below.
__global__ __launch_bounds__(256) void gemm_f16(
    const f16* __restrict__ A,
    const int* __restrict__ bidx,
    const f16* __restrict__ geneT, const f16* __restrict__ disT, int rowBase,
    const f16* __restrict__ Bt, const float* __restrict__ bias,
    f16* __restrict__ C, int M, int N, int K, int relu, int CB, int RB,
    const float* __restrict__ W4, float* __restrict__ outF)
{
    alignas(16) __shared__ f16 sA[128 * 64];
    alignas(16) __shared__ f16 sB[128 * 64];
    const int t = threadIdx.x;
    const int w = t >> 6, l = t & 63;
    const int wm = w >> 1, wn = w & 1;
    const int q = l >> 4, lr = l & 15;

    int flat = blockIdx.x;
    int cb, rb;
    if ((RB & 7) == 0) {
        int x = flat & 7, idx = flat >> 3;
        int Sx = RB >> 3;
        cb = idx % CB;
        rb = x * Sx + idx / CB;
    } else {
        cb = flat % CB;
        rb = flat / CB;
    }
    const int mBase = rb * 128, nBase = cb * 128;

    const int subrow = l >> 3;   // 0..7
    const int c = l & 7;         // 16B chunk 0..7 within a 128B row
    const char* pA[4];
    const char* pD[4];
    const char* pB[4];
    const bool fused = (bidx != nullptr);
    const bool concat = (!fused && disT != nullptr);
    const bool twoSrc = fused || concat;
#pragma unroll
    for (int j = 0; j < 4; j++) {
        int seg = j * 4 + w;
        int lrow = seg * 8 + subrow;               // 0..127
        int coff = ((c ^ (lrow & 7)) << 4);        // swizzled chunk byte offset
        if (fused) {
            int rg = rowBase + mBase + lrow;       // M % 128 == 0 on this path
            int gi = bidx[2 * rg], di = bidx[2 * rg + 1];
            pA[j] = (const char*)geneT + (size_t)gi * 512 + coff;
            pD[j] = (const char*)disT + (size_t)di * 512 + coff;
        } else if (concat) {
            int arow = mBase + lrow; if (arow > M - 1) arow = M - 1;
            pA[j] = (const char*)geneT + (size_t)arow * 512 + coff;
            pD[j] = (const char*)disT + (size_t)arow * 512 + coff;
        } else {
            int arow = mBase + lrow; if (arow > M - 1) arow = M - 1;
            pA[j] = (const char*)A + (size_t)arow * K * 2 + coff;
            pD[j] = nullptr;
        }
        int brow = nBase + lrow; if (brow > N - 1) brow = N - 1;
        pB[j] = (const char*)Bt + (size_t)brow * K * 2 + coff;
    }

    f32x4 acc[4][4] = {};

    for (int k0 = 0; k0 < K; k0 += 64) {
        __syncthreads();
#pragma unroll
        for (int j = 0; j < 4; j++) {
            int seg = j * 4 + w;
            const char* srcA;
            if (twoSrc)
                srcA = (k0 < 256) ? (pA[j] + (size_t)k0 * 2) : (pD[j] + (size_t)(k0 - 256) * 2);
            else
                srcA = pA[j] + (size_t)k0 * 2;
            gl_lds16(srcA, sA + seg * 512);
            gl_lds16(pB[j] + (size_t)k0 * 2, sB + seg * 512);
        }
        __syncthreads();
        f16x8 a0[4], a1[4], b0[4], b1[4];
#pragma unroll
        for (int i = 0; i < 4; i++) {
            int r = wm * 64 + i * 16 + lr;
            int rs = r * 64;
            int x0 = (q ^ (r & 7)) << 3;
            int x1 = ((4 + q) ^ (r & 7)) << 3;
            a0[i] = *(const f16x8*)(sA + rs + x0);
            a1[i] = *(const f16x8*)(sA + rs + x1);
        }
#pragma unroll
        for (int jj = 0; jj < 4; jj++) {
            int r = wn * 64 + jj * 16 + lr;
            int rs = r * 64;
            int x0 = (q ^ (r & 7)) << 3;
            int x1 = ((4 + q) ^ (r & 7)) << 3;
            b0[jj] = *(const f16x8*)(sB + rs + x0);
            b1[jj] = *(const f16x8*)(sB + rs + x1);
        }
#pragma unroll
        for (int i = 0; i < 4; i++)
#pragma unroll
            for (int jj = 0; jj < 4; jj++) {
                acc[i][jj] = __builtin_amdgcn_mfma_f32_16x16x32_f16(a0[i], b0[jj], acc[i][jj], 0, 0, 0);
                acc[i][jj] = __builtin_amdgcn_mfma_f32_16x16x32_f16(a1[i], b1[jj], acc[i][jj], 0, 0, 0);
            }
    }

    if (W4 != nullptr) {
        // fused final linear: out[rowBase+row] += lrelu(acc + bias) @ W4 (512x2)
        float w40[4], w41[4];
#pragma unroll
        for (int j = 0; j < 4; j++) {
            int col = nBase + wn * 64 + j * 16 + lr;
            w40[j] = W4[col * 2];
            w41[j] = W4[col * 2 + 1];
        }
#pragma unroll
        for (int i = 0; i < 4; i++) {
#pragma unroll
            for (int r = 0; r < 4; r++) {
                int row = mBase + wm * 64 + i * 16 + q * 4 + r;
                float s0 = 0.f, s1 = 0.f;
#pragma unroll
                for (int j = 0; j < 4; j++) {
                    int col = nBase + wn * 64 + j * 16 + lr;
                    float v = acc[i][j][r] + bias[col];
                    v = v >= 0.f ? v : 0.01f * v;
                    v = clampf(v);
                    s0 += v * w40[j];
                    s1 += v * w41[j];
                }
#pragma unroll
                for (int off = 1; off < 16; off <<= 1) {
                    s0 += __shfl_xor(s0, off);
                    s1 += __shfl_xor(s1, off);
                }
                if (lr == 0 && row < M) {
                    atomicAdd(&outF[(size_t)(rowBase + row) * 2], s0);
                    atomicAdd(&outF[(size_t)(rowBase + row) * 2 + 1], s1);
                }
            }
        }
        return;
    }

    // ---- epilogue: per-wave LDS transpose, then coalesced f16x8 stores ----
    __syncthreads();
    f16* lt = ((w >> 1) ? sB : sA) + (w & 1) * 4096;

    float bj[4];
#pragma unroll
    for (int j = 0; j < 4; j++)
        bj[j] = bias ? bias[nBase + wn * 64 + j * 16 + lr] : 0.f;

#pragma unroll
    for (int i = 0; i < 4; i++)
#pragma unroll
        for (int j = 0; j < 4; j++) {
            int col = j * 16 + lr;
#pragma unroll
            for (int r = 0; r < 4; r++) {
                int row = i * 16 + q * 4 + r;       // 0..63 wave-local
                float v = acc[i][j][r] + bj[j];
                if (relu) v = v >= 0.f ? v : 0.01f * v;
                v = clampf(v);
                int cs = col ^ ((((row >> 2) & 3) << 4) ^ ((row & 3) << 3));
                lt[row * 64 + cs] = (f16)v;
            }
        }
    __syncthreads();

    const int rr = l >> 3;
    const int c8 = l & 7;
#pragma unroll
    for (int it = 0; it < 8; it++) {
        int row = it * 8 + rr;
        int cs = (c8 * 8) ^ ((((row >> 2) & 3) << 4) ^ ((row & 3) << 3));
        f16x8 vv = *(const f16x8*)(lt + row * 64 + cs);
        int grow = mBase + wm * 64 + row;
        if (grow < M)
            *(f16x8*)(C + (size_t)grow * N + nBase + wn * 64 + c8 * 8) = vv;
    }
}

// ---------------- tower GEMM (separate copy: concat staging + stats + BN fold) -------
// y = lrelu([X|XA] @ Bt^T + bias + deg*c2), fused column stats into stats[0..511].
// Dedicated kernel so its fatter epilogue regalloc doesn't tax the head GEMMs.
__global__ __launch_bounds__(256) void gemm_tower(
    const f16* __restrict__ X, const f16* __restrict__ XA,
    const f16* __restrict__ Bt, const float* __restrict__ bias,
    f16* __restrict__ C, int M, int N, int K, int CB, int RB,
    float* __restrict__ stats, const float* __restrict__ c2,
    const int* __restrict__ deg)
{
    alignas(16) __shared__ f16 sA[128 * 64];
    alignas(16) __shared__ f16 sB[128 * 64];
    const int t = threadIdx.x;
    const int w = t >> 6, l = t & 63;
    const int wm = w >> 1, wn = w & 1;
    const int q = l >> 4, lr = l & 15;

    int flat = blockIdx.x;
    int cb, rb;
    if ((RB & 7) == 0) {
        int x = flat & 7, idx = flat >> 3;
        int Sx = RB >> 3;
        cb = idx % CB;
        rb = x * Sx + idx / CB;
    } else {
        cb = flat % CB;
        rb = flat / CB;
    }
    const int mBase = rb * 128, nBase = cb * 128;

    const int subrow = l >> 3;
    const int c = l & 7;
    const char* pA[4];
    const char* pD[4];
    const char* pB[4];
#pragma unroll
    for (int j = 0; j < 4; j++) {
        int seg = j * 4 + w;
        int lrow = seg * 8 + subrow;
        int coff = ((c ^ (lrow & 7)) << 4);
        int arow = mBase + lrow; if (arow > M - 1) arow = M - 1;
        pA[j] = (const char*)X + (size_t)arow * 512 + coff;
        pD[j] = (const char*)XA + (size_t)arow * 512 + coff;
        int brow = nBase + lrow; if (brow > N - 1) brow = N - 1;
        pB[j] = (const char*)Bt + (size_t)brow * K * 2 + coff;
    }

    f32x4 acc[4][4] = {};

    for (int k0 = 0; k0 < K; k0 += 64) {
        __syncthreads();
#pragma unroll
        for (int j = 0; j < 4; j++) {
            int seg = j * 4 + w;
            const char* srcA = (k0 < 256) ? (pA[j] + (size_t)k0 * 2)
                                          : (pD[j] + (size_t)(k0 - 256) * 2);
            gl_lds16(srcA, sA + seg * 512);
            gl_lds16(pB[j] + (size_t)k0 * 2, sB + seg * 512);
        }
        __syncthreads();
        f16x8 a0[4], a1[4], b0[4], b1[4];
#pragma unroll
        for (int i = 0; i < 4; i++) {
            int r = wm * 64 + i * 16 + lr;
            int rs = r * 64;
            int x0 = (q ^ (r & 7)) << 3;
            int x1 = ((4 + q) ^ (r & 7)) << 3;
            a0[i] = *(const f16x8*)(sA + rs + x0);
            a1[i] = *(const f16x8*)(sA + rs + x1);
        }
#pragma unroll
        for (int jj = 0; jj < 4; jj++) {
            int r = wn * 64 + jj * 16 + lr;
            int rs = r * 64;
            int x0 = (q ^ (r & 7)) << 3;
            int x1 = ((4 + q) ^ (r & 7)) << 3;
            b0[jj] = *(const f16x8*)(sB + rs + x0);
            b1[jj] = *(const f16x8*)(sB + rs + x1);
        }
#pragma unroll
        for (int i = 0; i < 4; i++)
#pragma unroll
            for (int jj = 0; jj < 4; jj++) {
                acc[i][jj] = __builtin_amdgcn_mfma_f32_16x16x32_f16(a0[i], b0[jj], acc[i][jj], 0, 0, 0);
                acc[i][jj] = __builtin_amdgcn_mfma_f32_16x16x32_f16(a1[i], b1[jj], acc[i][jj], 0, 0, 0);
            }
    }

    // ---- epilogue: bias + deg*c2, lrelu, fused stats, LDS transpose, store ----
    __syncthreads();
    f16* lt = ((w >> 1) ? sB : sA) + (w & 1) * 4096;

    float bj[4], c2j[4];
#pragma unroll
    for (int j = 0; j < 4; j++) {
        int col = nBase + wn * 64 + j * 16 + lr;
        bj[j] = bias[col];
        c2j[j] = c2[col];
    }

    float sj[4] = {0.f, 0.f, 0.f, 0.f}, s2j[4] = {0.f, 0.f, 0.f, 0.f};
#pragma unroll
    for (int i = 0; i < 4; i++) {
        float degf[4];
        int grow0 = mBase + wm * 64 + i * 16 + q * 4;
#pragma unroll
        for (int r = 0; r < 4; r++) {
            int gr = grow0 + r;
            degf[r] = (gr < M) ? (float)deg[gr] : 0.f;
        }
#pragma unroll
        for (int j = 0; j < 4; j++) {
            int col = j * 16 + lr;
#pragma unroll
            for (int r = 0; r < 4; r++) {
                int row = i * 16 + q * 4 + r;
                float v = acc[i][j][r] + bj[j] + degf[r] * c2j[j];
                v = v >= 0.f ? v : 0.01f * v;
                v = clampf(v);
                if ((mBase + wm * 64 + row) < M) { sj[j] += v; s2j[j] += v * v; }
                int cs = col ^ ((((row >> 2) & 3) << 4) ^ ((row & 3) << 3));
                lt[row * 64 + cs] = (f16)v;
            }
        }
    }

    // reduce over q (lanes ^16, ^32 share lr), one atomic pair per column per wave
#pragma unroll
    for (int j = 0; j < 4; j++) {
        float s = sj[j], s2 = s2j[j];
        s += __shfl_xor(s, 16); s2 += __shfl_xor(s2, 16);
        s += __shfl_xor(s, 32); s2 += __shfl_xor(s2, 32);
        if (q == 0) {
            int col = nBase + wn * 64 + j * 16 + lr;
            if (col < N) {
                atomicAdd(&stats[col], s);
                atomicAdd(&stats[256 + col], s2);
            }
        }
    }
    __syncthreads();

    const int rr = l >> 3;
    const int c8 = l & 7;
#pragma unroll
    for (int it = 0; it < 8; it++) {
        int row = it * 8 + rr;
        int cs = (c8 * 8) ^ ((((row >> 2) & 3) << 4) ^ ((row & 3) << 3));
        f16x8 vv = *(const f16x8*)(lt + row * 64 + cs);
        int grow = mBase + wm * 64 + row;
        if (grow < M)
            *(f16x8*)(C + (size_t)grow * N + nBase + wn * 64 + c8 * 8) = vv;
    }
}

// ---------------- small kernels ----------------
__global__ void cvt_f32_f16(const float* __restrict__ in, f16* __restrict__ out, size_t n) {
    size_t i = ((size_t)blockIdx.x * 256 + threadIdx.x) * 8;
    if (i >= n) return;
    f32x4 a = *(const f32x4*)(in + i);
    f32x4 b = *(const f32x4*)(in + i + 4);
    f16x8 o;
    o[0] = (f16)clampf(a.x); o[1] = (f16)clampf(a.y);
    o[2] = (f16)clampf(a.z); o[3] = (f16)clampf(a.w);
    o[4] = (f16)clampf(b.x); o[5] = (f16)clampf(b.y);
    o[6] = (f16)clampf(b.z); o[7] = (f16)clampf(b.w);
    *(f16x8*)(out + i) = o;
}

__global__ void init_out(const float* __restrict__ b4, float* __restrict__ out, int n) {
    int i = blockIdx.x * 256 + threadIdx.x;
    if (i < n) out[i] = b4[i & 1];
}

__global__ void count_deg(const int* __restrict__ ei, int E, int* __restrict__ deg) {
    int e = blockIdx.x * 256 + threadIdx.x;
    if (e < E) atomicAdd(&deg[ei[E + e]], 1);
}

__global__ void scan_deg(const int* __restrict__ deg, int* __restrict__ rowptr, int Nn) {
    __shared__ int part[1024];
    const int t = threadIdx.x;
    const int C = (Nn + 1023) >> 10;
    const int base = t * C;
    int s = 0;
    for (int i = 0; i < C; i++) { int idx = base + i; if (idx < Nn) s += deg[idx]; }
    part[t] = s;
    __syncthreads();
    for (int off = 1; off < 1024; off <<= 1) {
        int v = (t >= off) ? part[t - off] : 0;
        __syncthreads();
        part[t] += v;
        __syncthreads();
    }
    int pre = (t == 0) ? 0 : part[t - 1];
    for (int i = 0; i < C; i++) {
        int idx = base + i;
        if (idx < Nn) { rowptr[idx] = pre; pre += deg[idx]; }
    }
    if (t == 1023) rowptr[Nn] = part[1023];
}

__global__ void fill_csr(const int* __restrict__ ei, int E, const int* __restrict__ rowptr,
                         int* __restrict__ cursor, int* __restrict__ csr) {
    int e = blockIdx.x * 256 + threadIdx.x;
    if (e < E) {
        int d = ei[E + e];
        int p = rowptr[d] + atomicAdd(&cursor[d], 1);
        csr[p] = ei[e];
    }
}

// pre-aggregation (GraphConv linearity): XA[i] = sum_{j->i} X[j]  (X = raw y)
__global__ void agg_x(const int* __restrict__ rowptr, const int* __restrict__ csr,
                      const f16* __restrict__ X, f16* __restrict__ XA, int Nn) {
    int gid = blockIdx.x * 256 + threadIdx.x;
    int node = gid >> 6, l = gid & 63;
    if (node >= Nn) return;
    int beg = rowptr[node], end = rowptr[node + 1];
    float s0 = 0.f, s1 = 0.f, s2 = 0.f, s3 = 0.f;
    for (int e = beg; e < end; e++) {
        int src = csr[e];
        f16x4 xv = *(const f16x4*)(X + (size_t)src * 256 + l * 4);
        s0 += (float)xv.x; s1 += (float)xv.y; s2 += (float)xv.z; s3 += (float)xv.w;
    }
    f16x4 o;
    o.x = (f16)clampf(s0); o.y = (f16)clampf(s1);
    o.z = (f16)clampf(s2); o.w = (f16)clampf(s3);
    *(f16x4*)(XA + (size_t)node * 256 + l * 4) = o;
}

// Tiled transpose: WT[(dstRowOff+n)*LK + dstColOff + k] = W[k][n] * (scale?scale[k]:1)
__global__ void transpose_tile(const float* __restrict__ W, f16* __restrict__ WT,
                               int K, int N, int dstRowOff, int dstColOff, int LK,
                               const float* __restrict__ scale) {
    __shared__ float tile[32][33];
    int n0 = blockIdx.x * 32, k0 = blockIdx.y * 32;
    int tx = threadIdx.x, ty = threadIdx.y;
    for (int yy = ty; yy < 32; yy += 8) {
        int k = k0 + yy, n = n0 + tx;
        tile[yy][tx] = (k < K && n < N) ? W[(size_t)k * N + n] : 0.f;
    }
    __syncthreads();
    float sc = 1.f;
    if (scale) { int k = k0 + tx; if (k < K) sc = scale[k]; }
    for (int yy = ty; yy < 32; yy += 8) {
        int n = n0 + yy, k = k0 + tx;
        if (n < N && k < K)
            WT[(size_t)(dstRowOff + n) * LK + dstColOff + k] = (f16)clampf(tile[tx][yy] * sc);
    }
}

// BN coefficients from batch stats: s = g/sqrt(var+eps), t = b - mean*s
__global__ void compute_st(const float* __restrict__ stats, const float* __restrict__ g,
                           const float* __restrict__ b, float invN, float* __restrict__ st) {
    int col = threadIdx.x;   // 256
    float m = stats[col] * invN;
    float var = stats[256 + col] * invN - m * m;
    if (var < 0.f) var = 0.f;
    float rs = 1.0f / sqrtf(var + 1e-5f);
    float s = g[col] * rs;
    st[col] = s;
    st[256 + col] = b[col] - m * s;
}

// bias corrections for the BN fold: cbias[n] = br[n] + sum_k t[k]*Ws[k][n];
// c2[n] = sum_k t[k]*Wr[k][n]  (applied as deg_i * c2[n] in the GEMM epilogue)
__global__ void bias_corr(const float* __restrict__ st, const float* __restrict__ Ws,
                          const float* __restrict__ Wr, const float* __restrict__ br,
                          float* __restrict__ cbias, float* __restrict__ c2) {
    int n = threadIdx.x;   // 256
    float s1 = br[n], s2 = 0.f;
    for (int k = 0; k < 256; k++) {
        float tk = st[256 + k];
        s1 += tk * Ws[k * 256 + n];
        s2 += tk * Wr[k * 256 + n];
    }
    cbias[n] = s1;
    c2[n] = s2;
}

// tout = clamp( sum_l w_l * (y_l * s_l + t_l) ), BN applied in f32 here.
__global__ void combine3(const f16* __restrict__ y0, const f16* __restrict__ y1,
                         const f16* __restrict__ y2, const float* __restrict__ stA,
                         f16* __restrict__ tout, size_t total) {
    size_t i = ((size_t)blockIdx.x * 256 + threadIdx.x) * 8;
    if (i >= total) return;
    int colb = (int)(i & 255);
    f16x8 a = *(const f16x8*)(y0 + i);
    f16x8 b = *(const f16x8*)(y1 + i);
    f16x8 c = *(const f16x8*)(y2 + i);
    f16x8 o;
#pragma unroll
    for (int j = 0; j < 8; j++) {
        int col = colb + j;
        float v = 0.7f * ((float)a[j] * stA[col]        + stA[256 + col])
                + 0.2f * ((float)b[j] * stA[512 + col]  + stA[768 + col])
                + 0.1f * ((float)c[j] * stA[1024 + col] + stA[1280 + col]);
        o[j] = (f16)clampf(v);
    }
    *(f16x8*)(tout + i) = o;
}

extern "C" void kernel_launch(void* const* d_in, const int* in_sizes, int n_in,
                              void* d_out, int out_size, void* d_ws, size_t ws_size,
                              hipStream_t stream) {
    char* ws = (char*)d_ws;
    size_t off = 0;
    auto alloc = [&](size_t bytes) -> void* {
        void* p = ws + off;
        off += (bytes + 255) & ~(size_t)255;
        return p;
    };

    // persistent (~46 MB)
    f16* gene_out = (f16*)alloc((size_t)N_G * 256 * 2);
    f16* dis_out  = (f16*)alloc((size_t)N_D * 256 * 2);
    f16* W1T = (f16*)alloc((size_t)2048 * 512 * 2);
    f16* W2T = (f16*)alloc((size_t)1024 * 2048 * 2);
    f16* W3T = (f16*)alloc((size_t)512 * 1024 * 2);
    f16* WcatT = (f16*)alloc((size_t)256 * 512 * 2);
    int* csr = (int*)alloc((size_t)E_G * 4);
    int* rowptr = (int*)alloc((size_t)(N_G + 1) * 4);
    int* cnt = (int*)alloc((size_t)N_G * 4);
    int* deg = (int*)alloc((size_t)N_G * 4);
    float* statsAll = (float*)alloc(3 * 512 * 4);
    float* stAll = (float*)alloc(3 * 512 * 4);
    float* cbias = (float*)alloc(256 * 4);
    float* c2buf = (float*)alloc(256 * 4);

    char* scratch = ws + off;
    size_t avail = (ws_size > off) ? (ws_size - off) : 0;

    // tower buffers: X0, y0, y1, y2, XA  (N_G stride, 5 x 25.6 MB = 128 MB)
    const size_t NS = (size_t)N_G * 256;
    f16* X0 = (f16*)scratch;
    f16* y0 = X0 + NS;
    f16* y1 = y0 + NS;
    f16* y2 = y1 + NS;
    f16* XAbuf = y2 + NS;

    // head chunk: R rows use R*6144 bytes (h1 4KB + h2 2KB per row)
    int R = 32768;
    while ((size_t)R * 6144 > avail && R > 256) R >>= 1;
    int chunks = BATCH / R;
    f16* h1 = (f16*)scratch;
    f16* h2 = h1 + (size_t)R * 2048;

    const float* gene_x = (const float*)d_in[0];
    const float* disease_x = (const float*)d_in[1];
    const int* g_ei = (const int*)d_in[2];
    const int* d_ei = (const int*)d_in[3];
    const int* bidx = (const int*)d_in[4];
    float* out = (float*)d_out;

    auto run_tower = [&](const float* xin, const int* ei, int Nn, int E, int pbase, f16* tout) {
        size_t nelem = (size_t)Nn * 256;
        int nb8 = (int)((nelem / 8 + 255) / 256);
        cvt_f32_f16<<<nb8, 256, 0, stream>>>(xin, X0, nelem);
        hipMemsetAsync(deg, 0, (size_t)Nn * 4, stream);
        count_deg<<<(E + 255) / 256, 256, 0, stream>>>(ei, E, deg);
        scan_deg<<<1, 1024, 0, stream>>>(deg, rowptr, Nn);
        hipMemsetAsync(cnt, 0, (size_t)Nn * 4, stream);
        fill_csr<<<(E + 255) / 256, 256, 0, stream>>>(ei, E, rowptr, cnt, csr);
        hipMemsetAsync(statsAll, 0, 3 * 512 * 4, stream);
        hipMemsetAsync(c2buf, 0, 256 * 4, stream);   // layer-0: deg*0 correction
        int RB = (Nn + 127) / 128;
        int RBp = (RB + 7) & ~7;
        const f16* yin = X0;
        f16* youts[3] = {y0, y1, y2};
        for (int l = 0; l < 3; l++) {
            const float* Wr = (const float*)d_in[pbase + l * 5 + 0];
            const float* br = (const float*)d_in[pbase + l * 5 + 1];
            const float* Wss = (const float*)d_in[pbase + l * 5 + 2];
            const float* bg = (const float*)d_in[pbase + l * 5 + 3];
            const float* bb = (const float*)d_in[pbase + l * 5 + 4];
            const float* biasP;
            const float* stPrev = (l > 0) ? (stAll + (l - 1) * 512) : nullptr;
            if (l == 0) {
                biasP = br;
                transpose_tile<<<dim3(8, 8), dim3(32, 8), 0, stream>>>(Wss, WcatT, 256, 256, 0, 0, 512, nullptr);
                transpose_tile<<<dim3(8, 8), dim3(32, 8), 0, stream>>>(Wr, WcatT, 256, 256, 0, 256, 512, nullptr);
            } else {
                // BN fold: scaled weights + bias corrections from (s,t) of prev layer
                bias_corr<<<1, 256, 0, stream>>>(stPrev, Wss, Wr, br, cbias, c2buf);
                transpose_tile<<<dim3(8, 8), dim3(32, 8), 0, stream>>>(Wss, WcatT, 256, 256, 0, 0, 512, stPrev);
                transpose_tile<<<dim3(8, 8), dim3(32, 8), 0, stream>>>(Wr, WcatT, 256, 256, 0, 256, 512, stPrev);
                biasP = cbias;
            }
            agg_x<<<(Nn * 64 + 255) / 256, 256, 0, stream>>>(rowptr, csr, yin, XAbuf, Nn);
            // y_l = lrelu([X|XA] @ [s*Ws ; s*Wr] + cbias + deg*c2), fused stats
            gemm_tower<<<2 * RBp, 256, 0, stream>>>(yin, XAbuf, WcatT, biasP, youts[l],
                                                    Nn, 256, 512, 2, RBp,
                                                    statsAll + l * 512, c2buf, deg);
            compute_st<<<1, 256, 0, stream>>>(statsAll + l * 512, bg, bb, 1.0f / Nn, stAll + l * 512);
            yin = youts[l];
        }
        combine3<<<nb8, 256, 0, stream>>>(y0, y1, y2, stAll, tout, nelem);
    };

    run_tower(gene_x, g_ei, N_G, E_G, 5, gene_out);
    run_tower(disease_x, d_ei, N_D, E_D, 20, dis_out);

    const float* lin1_W = (const float*)d_in[35];
    const float* lin1_b = (const float*)d_in[36];
    const float* lin2_W = (const float*)d_in[37];
    const float* lin2_b = (const float*)d_in[38];
    const float* lin3_W = (const float*)d_in[39];
    const float* lin3_b = (const float*)d_in[40];
    const float* lin4_W = (const float*)d_in[41];
    const float* lin4_b = (const float*)d_in[42];

    transpose_tile<<<dim3(64, 16), dim3(32, 8), 0, stream>>>(lin1_W, W1T, 512, 2048, 0, 0, 512, nullptr);
    transpose_tile<<<dim3(32, 64), dim3(32, 8), 0, stream>>>(lin2_W, W2T, 2048, 1024, 0, 0, 2048, nullptr);
    transpose_tile<<<dim3(16, 32), dim3(32, 8), 0, stream>>>(lin3_W, W3T, 1024, 512, 0, 0, 1024, nullptr);
    init_out<<<(BATCH * 2 + 255) / 256, 256, 0, stream>>>(lin4_b, out, BATCH * 2);

    for (int c = 0; c < chunks; c++) {
        int rb = c * R;
        int RB = R / 128;
        // lin1 with fused pair-gather from gene_out/dis_out
        gemm_f16<<<16 * RB, 256, 0, stream>>>(nullptr, bidx, gene_out, dis_out, rb,
                                              W1T, lin1_b, h1, R, 2048, 512, 1, 16, RB,
                                              nullptr, nullptr);
        gemm_f16<<<8 * RB, 256, 0, stream>>>(h1, nullptr, nullptr, nullptr, 0,
                                             W2T, lin2_b, h2, R, 1024, 2048, 1, 8, RB,
                                             nullptr, nullptr);
        // lin3 with fused lin4: atomics into out (fp32)
        gemm_f16<<<4 * RB, 256, 0, stream>>>(h2, nullptr, nullptr, nullptr, rb,
                                             W3T, lin3_b, nullptr, R, 512, 1024, 1, 4, RB,
                                             lin4_W, out);
    }
}

// Round 9
// 1556.804 us; speedup vs baseline: 1.0321x; 1.0321x over previous
//
#include <hip/hip_runtime.h>
#include <hip/hip_bf16.h>
#include <cstdint>
#include <cstddef>

#define N_G 50000
#define N_D 20000
#define E_G 300000
#define E_D 150000
#define BATCH 65536

typedef _Float16 f16;
typedef _Float16 f16x8 __attribute__((ext_vector_type(8)));
typedef _Float16 f16x4 __attribute__((ext_vector_type(4)));
typedef float f32x4 __attribute__((ext_vector_type(4)));

__device__ __forceinline__ float clampf(float v) {
    return fminf(fmaxf(v, -60000.f), 60000.f);  // also squashes NaN
}

__device__ __forceinline__ void gl_lds16(const void* g, void* l) {
    __builtin_amdgcn_global_load_lds(
        (const __attribute__((address_space(1))) unsigned int*)g,
        (__attribute__((address_space(3))) unsigned int*)l, 16, 0, 0);
}

// ---------------- GEMM (128x128, 4 waves): C = act(A @ Bt^T + bias) ----------------
// Pure 84-VGPR form (R15-verified). Used for lin2 (plain) and lin3 (+fused lin4).
__global__ __launch_bounds__(256) void gemm_f16(
    const f16* __restrict__ A,
    const int* __restrict__ bidx,
    const f16* __restrict__ geneT, const f16* __restrict__ disT, int rowBase,
    const f16* __restrict__ Bt, const float* __restrict__ bias,
    f16* __restrict__ C, int M, int N, int K, int relu, int CB, int RB,
    const float* __restrict__ W4, float* __restrict__ outF)
{
    alignas(16) __shared__ f16 sA[128 * 64];
    alignas(16) __shared__ f16 sB[128 * 64];
    const int t = threadIdx.x;
    const int w = t >> 6, l = t & 63;
    const int wm = w >> 1, wn = w & 1;
    const int q = l >> 4, lr = l & 15;

    int flat = blockIdx.x;
    int cb, rb;
    if ((RB & 7) == 0) {
        int x = flat & 7, idx = flat >> 3;
        int Sx = RB >> 3;
        cb = idx % CB;
        rb = x * Sx + idx / CB;
    } else {
        cb = flat % CB;
        rb = flat / CB;
    }
    const int mBase = rb * 128, nBase = cb * 128;

    const int subrow = l >> 3;   // 0..7
    const int c = l & 7;         // 16B chunk 0..7 within a 128B row
    const char* pA[4];
    const char* pD[4];
    const char* pB[4];
    const bool fused = (bidx != nullptr);
    const bool concat = (!fused && disT != nullptr);
    const bool twoSrc = fused || concat;
#pragma unroll
    for (int j = 0; j < 4; j++) {
        int seg = j * 4 + w;
        int lrow = seg * 8 + subrow;               // 0..127
        int coff = ((c ^ (lrow & 7)) << 4);        // swizzled chunk byte offset
        if (fused) {
            int rg = rowBase + mBase + lrow;       // M % 128 == 0 on this path
            int gi = bidx[2 * rg], di = bidx[2 * rg + 1];
            pA[j] = (const char*)geneT + (size_t)gi * 512 + coff;
            pD[j] = (const char*)disT + (size_t)di * 512 + coff;
        } else if (concat) {
            int arow = mBase + lrow; if (arow > M - 1) arow = M - 1;
            pA[j] = (const char*)geneT + (size_t)arow * 512 + coff;
            pD[j] = (const char*)disT + (size_t)arow * 512 + coff;
        } else {
            int arow = mBase + lrow; if (arow > M - 1) arow = M - 1;
            pA[j] = (const char*)A + (size_t)arow * K * 2 + coff;
            pD[j] = nullptr;
        }
        int brow = nBase + lrow; if (brow > N - 1) brow = N - 1;
        pB[j] = (const char*)Bt + (size_t)brow * K * 2 + coff;
    }

    f32x4 acc[4][4] = {};

    for (int k0 = 0; k0 < K; k0 += 64) {
        __syncthreads();
#pragma unroll
        for (int j = 0; j < 4; j++) {
            int seg = j * 4 + w;
            const char* srcA;
            if (twoSrc)
                srcA = (k0 < 256) ? (pA[j] + (size_t)k0 * 2) : (pD[j] + (size_t)(k0 - 256) * 2);
            else
                srcA = pA[j] + (size_t)k0 * 2;
            gl_lds16(srcA, sA + seg * 512);
            gl_lds16(pB[j] + (size_t)k0 * 2, sB + seg * 512);
        }
        __syncthreads();
        f16x8 a0[4], a1[4], b0[4], b1[4];
#pragma unroll
        for (int i = 0; i < 4; i++) {
            int r = wm * 64 + i * 16 + lr;
            int rs = r * 64;
            int x0 = (q ^ (r & 7)) << 3;
            int x1 = ((4 + q) ^ (r & 7)) << 3;
            a0[i] = *(const f16x8*)(sA + rs + x0);
            a1[i] = *(const f16x8*)(sA + rs + x1);
        }
#pragma unroll
        for (int jj = 0; jj < 4; jj++) {
            int r = wn * 64 + jj * 16 + lr;
            int rs = r * 64;
            int x0 = (q ^ (r & 7)) << 3;
            int x1 = ((4 + q) ^ (r & 7)) << 3;
            b0[jj] = *(const f16x8*)(sB + rs + x0);
            b1[jj] = *(const f16x8*)(sB + rs + x1);
        }
#pragma unroll
        for (int i = 0; i < 4; i++)
#pragma unroll
            for (int jj = 0; jj < 4; jj++) {
                acc[i][jj] = __builtin_amdgcn_mfma_f32_16x16x32_f16(a0[i], b0[jj], acc[i][jj], 0, 0, 0);
                acc[i][jj] = __builtin_amdgcn_mfma_f32_16x16x32_f16(a1[i], b1[jj], acc[i][jj], 0, 0, 0);
            }
    }

    if (W4 != nullptr) {
        // fused final linear: out[rowBase+row] += lrelu(acc + bias) @ W4 (512x2)
        float w40[4], w41[4];
#pragma unroll
        for (int j = 0; j < 4; j++) {
            int col = nBase + wn * 64 + j * 16 + lr;
            w40[j] = W4[col * 2];
            w41[j] = W4[col * 2 + 1];
        }
#pragma unroll
        for (int i = 0; i < 4; i++) {
#pragma unroll
            for (int r = 0; r < 4; r++) {
                int row = mBase + wm * 64 + i * 16 + q * 4 + r;
                float s0 = 0.f, s1 = 0.f;
#pragma unroll
                for (int j = 0; j < 4; j++) {
                    int col = nBase + wn * 64 + j * 16 + lr;
                    float v = acc[i][j][r] + bias[col];
                    v = v >= 0.f ? v : 0.01f * v;
                    v = clampf(v);
                    s0 += v * w40[j];
                    s1 += v * w41[j];
                }
#pragma unroll
                for (int off = 1; off < 16; off <<= 1) {
                    s0 += __shfl_xor(s0, off);
                    s1 += __shfl_xor(s1, off);
                }
                if (lr == 0 && row < M) {
                    atomicAdd(&outF[(size_t)(rowBase + row) * 2], s0);
                    atomicAdd(&outF[(size_t)(rowBase + row) * 2 + 1], s1);
                }
            }
        }
        return;
    }

    // ---- epilogue: per-wave LDS transpose, then coalesced f16x8 stores ----
    __syncthreads();
    f16* lt = ((w >> 1) ? sB : sA) + (w & 1) * 4096;

    float bj[4];
#pragma unroll
    for (int j = 0; j < 4; j++)
        bj[j] = bias ? bias[nBase + wn * 64 + j * 16 + lr] : 0.f;

#pragma unroll
    for (int i = 0; i < 4; i++)
#pragma unroll
        for (int j = 0; j < 4; j++) {
            int col = j * 16 + lr;
#pragma unroll
            for (int r = 0; r < 4; r++) {
                int row = i * 16 + q * 4 + r;       // 0..63 wave-local
                float v = acc[i][j][r] + bj[j];
                if (relu) v = v >= 0.f ? v : 0.01f * v;
                v = clampf(v);
                int cs = col ^ ((((row >> 2) & 3) << 4) ^ ((row & 3) << 3));
                lt[row * 64 + cs] = (f16)v;
            }
        }
    __syncthreads();

    const int rr = l >> 3;
    const int c8 = l & 7;
#pragma unroll
    for (int it = 0; it < 8; it++) {
        int row = it * 8 + rr;
        int cs = (c8 * 8) ^ ((((row >> 2) & 3) << 4) ^ ((row & 3) << 3));
        f16x8 vv = *(const f16x8*)(lt + row * 64 + cs);
        int grow = mBase + wm * 64 + row;
        if (grow < M)
            *(f16x8*)(C + (size_t)grow * N + nBase + wn * 64 + c8 * 8) = vv;
    }
}

// ---------------- GEMM 256x256, 8 waves, prefetch-distance-2 (R11-verified) ---------
// Used for lin1 only: the gathered A rows come from HBM/L3 and benefit from the
// 2-iteration prefetch cover + halved per-FLOP refetch of the 256 tile (R10/R11 data).
__global__ __launch_bounds__(512) void gemm256(
    const f16* __restrict__ A,
    const int* __restrict__ bidx,
    const f16* __restrict__ geneT, const f16* __restrict__ disT, int rowBase,
    const f16* __restrict__ Bt, const float* __restrict__ bias,
    f16* __restrict__ C, int M, int N, int K, int relu, int CB, int RB)
{
    alignas(16) __shared__ f16 sm[81920];   // A: 3x16384 | B: 2x16384 (f16 units)
    const int t = threadIdx.x;
    const int w = t >> 6, l = t & 63;
    const int wm = w >> 2, wn = w & 3;      // 2 x 4 wave grid
    const int q = l >> 4, lr = l & 15;

    int flat = blockIdx.x;
    int cb, rb;
    if ((RB & 7) == 0) {
        int x = flat & 7, idx = flat >> 3;
        int Sx = RB >> 3;
        cb = idx % CB;
        rb = x * Sx + idx / CB;
    } else {
        cb = flat % CB;
        rb = flat / CB;
    }
    const int mBase = rb * 256, nBase = cb * 256;

    const int subrow = l >> 3;   // 0..7
    const int c = l & 7;         // 16B chunk within a 128B row
    const bool gat = (bidx != nullptr);
    const char* pA[4];
    const char* pD[4];
    const char* pB[4];
#pragma unroll
    for (int jj = 0; jj < 4; jj++) {
        int arow = jj * 64 + w * 8 + subrow;        // 0..255 tile-local row
        int coff = ((c ^ (arow & 7)) << 4);         // inverse-swizzled source chunk
        if (gat) {
            int rg = rowBase + mBase + arow;        // M % 256 == 0 on this path
            int gi = bidx[2 * rg], di = bidx[2 * rg + 1];
            pA[jj] = (const char*)geneT + (size_t)gi * 512 + coff;
            pD[jj] = (const char*)disT + (size_t)di * 512 + coff;
        } else {
            int ga = mBase + arow; if (ga > M - 1) ga = M - 1;
            pA[jj] = (const char*)A + (size_t)ga * K * 2 + coff;
            pD[jj] = nullptr;
        }
        int gb = nBase + arow; if (gb > N - 1) gb = N - 1;
        pB[jj] = (const char*)Bt + (size_t)gb * K * 2 + coff;
    }

    f16* const smA = sm;                // 3 bufs
    f16* const smB = sm + 3 * 16384;    // 2 bufs

    auto stageA = [&](int abuf, int k0) {
        f16* bA = smA + abuf * 16384;
#pragma unroll
        for (int jj = 0; jj < 4; jj++) {
            int R0 = jj * 64 + w * 8;               // wave-uniform LDS row base
            const char* srcA;
            if (gat)
                srcA = (k0 < 256) ? (pA[jj] + (size_t)k0 * 2) : (pD[jj] + (size_t)(k0 - 256) * 2);
            else
                srcA = pA[jj] + (size_t)k0 * 2;
            gl_lds16(srcA, bA + R0 * 64);
        }
    };
    auto stageB = [&](int bbuf, int k0) {
        f16* bB = smB + bbuf * 16384;
#pragma unroll
        for (int jj = 0; jj < 4; jj++) {
            int R0 = jj * 64 + w * 8;
            gl_lds16(pB[jj] + (size_t)k0 * 2, bB + R0 * 64);
        }
    };

    f32x4 acc[8][4] = {};
    const int nkt = K >> 6;

    // prologue: A(0), B(0), A(1)
    stageA(0, 0);
    stageB(0, 0);
    if (nkt > 1) stageA(1, 64);

    for (int kt = 0; kt < nkt; kt++) {
        if (kt + 1 < nkt) stageB((kt + 1) & 1, (kt + 1) << 6);
        if (kt + 2 < nkt) stageA((kt + 2) % 3, (kt + 2) << 6);
        if (kt + 2 < nkt)      asm volatile("s_waitcnt vmcnt(12)" ::: "memory");
        else if (kt + 1 < nkt) asm volatile("s_waitcnt vmcnt(8)" ::: "memory");
        else                   asm volatile("s_waitcnt vmcnt(0)" ::: "memory");
        __builtin_amdgcn_s_barrier();
        __builtin_amdgcn_sched_barrier(0);
        const f16* bA = smA + (kt % 3) * 16384;
        const f16* bB = smB + (kt & 1) * 16384;
#pragma unroll
        for (int ks = 0; ks < 2; ks++) {
            f16x8 bf[4];
#pragma unroll
            for (int nf = 0; nf < 4; nf++) {
                int rB = wn * 64 + nf * 16 + lr;
                bf[nf] = *(const f16x8*)(bB + rB * 64 + ((((ks << 2) + q) ^ (rB & 7)) << 3));
            }
#pragma unroll
            for (int mf = 0; mf < 8; mf++) {
                int rA = wm * 128 + mf * 16 + lr;
                f16x8 af = *(const f16x8*)(bA + rA * 64 + ((((ks << 2) + q) ^ (rA & 7)) << 3));
#pragma unroll
                for (int nf = 0; nf < 4; nf++)
                    acc[mf][nf] = __builtin_amdgcn_mfma_f32_16x16x32_f16(af, bf[nf], acc[mf][nf], 0, 0, 0);
            }
        }
        __builtin_amdgcn_sched_barrier(0);
        __builtin_amdgcn_s_barrier();
    }
    __builtin_amdgcn_sched_barrier(0);

    // ---- epilogue: per-wave 128x64 LDS transpose (16KB slice), f16x8 stores ----
    f16* lt = sm + w * 8192;
    float bj[4];
#pragma unroll
    for (int nf = 0; nf < 4; nf++)
        bj[nf] = bias ? bias[nBase + wn * 64 + nf * 16 + lr] : 0.f;

#pragma unroll
    for (int mf = 0; mf < 8; mf++)
#pragma unroll
        for (int nf = 0; nf < 4; nf++) {
            int col = nf * 16 + lr;
#pragma unroll
            for (int r = 0; r < 4; r++) {
                int row = mf * 16 + q * 4 + r;      // 0..127 wave-local
                float v = acc[mf][nf][r] + bj[nf];
                if (relu) v = v >= 0.f ? v : 0.01f * v;
                v = clampf(v);
                int cs = col ^ ((((row >> 2) & 3) << 4) ^ ((row & 3) << 3));
                lt[row * 64 + cs] = (f16)v;
            }
        }

    const int rr = l >> 3;
    const int c8 = l & 7;
#pragma unroll
    for (int it = 0; it < 16; it++) {
        int row = it * 8 + rr;                      // 0..127 wave-local
        int cs = (c8 * 8) ^ ((((row >> 2) & 3) << 4) ^ ((row & 3) << 3));
        f16x8 vv = *(const f16x8*)(lt + row * 64 + cs);
        int grow = mBase + wm * 128 + row;
        if (grow < M)
            *(f16x8*)(C + (size_t)grow * N + nBase + wn * 64 + c8 * 8) = vv;
    }
}

// ---------------- tower GEMM (concat staging + fused column-stats, R10/R11 path) ----
// y = lrelu([X|XA] @ Bt^T + bias); stats[0..255]=sum, [256..511]=sumsq (for BN).
__global__ __launch_bounds__(256) void gemm_tower(
    const f16* __restrict__ X, const f16* __restrict__ XA,
    const f16* __restrict__ Bt, const float* __restrict__ bias,
    f16* __restrict__ C, int M, int N, int K, int CB, int RB,
    float* __restrict__ stats)
{
    alignas(16) __shared__ f16 sA[128 * 64];
    alignas(16) __shared__ f16 sB[128 * 64];
    const int t = threadIdx.x;
    const int w = t >> 6, l = t & 63;
    const int wm = w >> 1, wn = w & 1;
    const int q = l >> 4, lr = l & 15;

    int flat = blockIdx.x;
    int cb, rb;
    if ((RB & 7) == 0) {
        int x = flat & 7, idx = flat >> 3;
        int Sx = RB >> 3;
        cb = idx % CB;
        rb = x * Sx + idx / CB;
    } else {
        cb = flat % CB;
        rb = flat / CB;
    }
    const int mBase = rb * 128, nBase = cb * 128;

    const int subrow = l >> 3;
    const int c = l & 7;
    const char* pA[4];
    const char* pD[4];
    const char* pB[4];
#pragma unroll
    for (int j = 0; j < 4; j++) {
        int seg = j * 4 + w;
        int lrow = seg * 8 + subrow;
        int coff = ((c ^ (lrow & 7)) << 4);
        int arow = mBase + lrow; if (arow > M - 1) arow = M - 1;
        pA[j] = (const char*)X + (size_t)arow * 512 + coff;
        pD[j] = (const char*)XA + (size_t)arow * 512 + coff;
        int brow = nBase + lrow; if (brow > N - 1) brow = N - 1;
        pB[j] = (const char*)Bt + (size_t)brow * K * 2 + coff;
    }

    f32x4 acc[4][4] = {};

    for (int k0 = 0; k0 < K; k0 += 64) {
        __syncthreads();
#pragma unroll
        for (int j = 0; j < 4; j++) {
            int seg = j * 4 + w;
            const char* srcA = (k0 < 256) ? (pA[j] + (size_t)k0 * 2)
                                          : (pD[j] + (size_t)(k0 - 256) * 2);
            gl_lds16(srcA, sA + seg * 512);
            gl_lds16(pB[j] + (size_t)k0 * 2, sB + seg * 512);
        }
        __syncthreads();
        f16x8 a0[4], a1[4], b0[4], b1[4];
#pragma unroll
        for (int i = 0; i < 4; i++) {
            int r = wm * 64 + i * 16 + lr;
            int rs = r * 64;
            int x0 = (q ^ (r & 7)) << 3;
            int x1 = ((4 + q) ^ (r & 7)) << 3;
            a0[i] = *(const f16x8*)(sA + rs + x0);
            a1[i] = *(const f16x8*)(sA + rs + x1);
        }
#pragma unroll
        for (int jj = 0; jj < 4; jj++) {
            int r = wn * 64 + jj * 16 + lr;
            int rs = r * 64;
            int x0 = (q ^ (r & 7)) << 3;
            int x1 = ((4 + q) ^ (r & 7)) << 3;
            b0[jj] = *(const f16x8*)(sB + rs + x0);
            b1[jj] = *(const f16x8*)(sB + rs + x1);
        }
#pragma unroll
        for (int i = 0; i < 4; i++)
#pragma unroll
            for (int jj = 0; jj < 4; jj++) {
                acc[i][jj] = __builtin_amdgcn_mfma_f32_16x16x32_f16(a0[i], b0[jj], acc[i][jj], 0, 0, 0);
                acc[i][jj] = __builtin_amdgcn_mfma_f32_16x16x32_f16(a1[i], b1[jj], acc[i][jj], 0, 0, 0);
            }
    }

    // ---- epilogue: bias, lrelu, fused stats, LDS transpose, store ----
    __syncthreads();
    f16* lt = ((w >> 1) ? sB : sA) + (w & 1) * 4096;

    float bj[4];
#pragma unroll
    for (int j = 0; j < 4; j++)
        bj[j] = bias[nBase + wn * 64 + j * 16 + lr];

    float sj[4] = {0.f, 0.f, 0.f, 0.f}, s2j[4] = {0.f, 0.f, 0.f, 0.f};
#pragma unroll
    for (int i = 0; i < 4; i++)
#pragma unroll
        for (int j = 0; j < 4; j++) {
            int col = j * 16 + lr;
#pragma unroll
            for (int r = 0; r < 4; r++) {
                int row = i * 16 + q * 4 + r;
                float v = acc[i][j][r] + bj[j];
                v = v >= 0.f ? v : 0.01f * v;
                v = clampf(v);
                if ((mBase + wm * 64 + row) < M) { sj[j] += v; s2j[j] += v * v; }
                int cs = col ^ ((((row >> 2) & 3) << 4) ^ ((row & 3) << 3));
                lt[row * 64 + cs] = (f16)v;
            }
        }

    // reduce over q (lanes ^16, ^32 share lr), one atomic pair per column per wave
#pragma unroll
    for (int j = 0; j < 4; j++) {
        float s = sj[j], s2 = s2j[j];
        s += __shfl_xor(s, 16); s2 += __shfl_xor(s2, 16);
        s += __shfl_xor(s, 32); s2 += __shfl_xor(s2, 32);
        if (q == 0) {
            int col = nBase + wn * 64 + j * 16 + lr;
            if (col < N) {
                atomicAdd(&stats[col], s);
                atomicAdd(&stats[256 + col], s2);
            }
        }
    }
    __syncthreads();

    const int rr = l >> 3;
    const int c8 = l & 7;
#pragma unroll
    for (int it = 0; it < 8; it++) {
        int row = it * 8 + rr;
        int cs = (c8 * 8) ^ ((((row >> 2) & 3) << 4) ^ ((row & 3) << 3));
        f16x8 vv = *(const f16x8*)(lt + row * 64 + cs);
        int grow = mBase + wm * 64 + row;
        if (grow < M)
            *(f16x8*)(C + (size_t)grow * N + nBase + wn * 64 + c8 * 8) = vv;
    }
}

// ---------------- small kernels ----------------
__global__ void cvt_f32_f16(const float* __restrict__ in, f16* __restrict__ out, size_t n) {
    size_t i = ((size_t)blockIdx.x * 256 + threadIdx.x) * 8;
    if (i >= n) return;
    f32x4 a = *(const f32x4*)(in + i);
    f32x4 b = *(const f32x4*)(in + i + 4);
    f16x8 o;
    o[0] = (f16)clampf(a.x); o[1] = (f16)clampf(a.y);
    o[2] = (f16)clampf(a.z); o[3] = (f16)clampf(a.w);
    o[4] = (f16)clampf(b.x); o[5] = (f16)clampf(b.y);
    o[6] = (f16)clampf(b.z); o[7] = (f16)clampf(b.w);
    *(f16x8*)(out + i) = o;
}

__global__ void init_out(const float* __restrict__ b4, float* __restrict__ out, int n) {
    int i = blockIdx.x * 256 + threadIdx.x;
    if (i < n) out[i] = b4[i & 1];
}

__global__ void count_deg(const int* __restrict__ ei, int E, int* __restrict__ deg) {
    int e = blockIdx.x * 256 + threadIdx.x;
    if (e < E) atomicAdd(&deg[ei[E + e]], 1);
}

__global__ void scan_deg(const int* __restrict__ deg, int* __restrict__ rowptr, int Nn) {
    __shared__ int part[1024];
    const int t = threadIdx.x;
    const int C = (Nn + 1023) >> 10;
    const int base = t * C;
    int s = 0;
    for (int i = 0; i < C; i++) { int idx = base + i; if (idx < Nn) s += deg[idx]; }
    part[t] = s;
    __syncthreads();
    for (int off = 1; off < 1024; off <<= 1) {
        int v = (t >= off) ? part[t - off] : 0;
        __syncthreads();
        part[t] += v;
        __syncthreads();
    }
    int pre = (t == 0) ? 0 : part[t - 1];
    for (int i = 0; i < C; i++) {
        int idx = base + i;
        if (idx < Nn) { rowptr[idx] = pre; pre += deg[idx]; }
    }
    if (t == 1023) rowptr[Nn] = part[1023];
}

__global__ void fill_csr(const int* __restrict__ ei, int E, const int* __restrict__ rowptr,
                         int* __restrict__ cursor, int* __restrict__ csr) {
    int e = blockIdx.x * 256 + threadIdx.x;
    if (e < E) {
        int d = ei[E + e];
        int p = rowptr[d] + atomicAdd(&cursor[d], 1);
        csr[p] = ei[e];
    }
}

// pre-aggregation (GraphConv linearity): XA[i] = sum_{j->i} X[j]
__global__ void agg_x(const int* __restrict__ rowptr, const int* __restrict__ csr,
                      const f16* __restrict__ X, f16* __restrict__ XA, int Nn) {
    int gid = blockIdx.x * 256 + threadIdx.x;
    int node = gid >> 6, l = gid & 63;
    if (node >= Nn) return;
    int beg = rowptr[node], end = rowptr[node + 1];
    float s0 = 0.f, s1 = 0.f, s2 = 0.f, s3 = 0.f;
    for (int e = beg; e < end; e++) {
        int src = csr[e];
        f16x4 xv = *(const f16x4*)(X + (size_t)src * 256 + l * 4);
        s0 += (float)xv.x; s1 += (float)xv.y; s2 += (float)xv.z; s3 += (float)xv.w;
    }
    f16x4 o;
    o.x = (f16)clampf(s0); o.y = (f16)clampf(s1);
    o.z = (f16)clampf(s2); o.w = (f16)clampf(s3);
    *(f16x4*)(XA + (size_t)node * 256 + l * 4) = o;
}

// Tiled transpose: WT[(dstRowOff+n)*LK + dstColOff + k] = W[k][n]
__global__ void transpose_tile(const float* __restrict__ W, f16* __restrict__ WT,
                               int K, int N, int dstRowOff, int dstColOff, int LK) {
    __shared__ float tile[32][33];
    int n0 = blockIdx.x * 32, k0 = blockIdx.y * 32;
    int tx = threadIdx.x, ty = threadIdx.y;
    for (int yy = ty; yy < 32; yy += 8) {
        int k = k0 + yy, n = n0 + tx;
        tile[yy][tx] = (k < K && n < N) ? W[(size_t)k * N + n] : 0.f;
    }
    __syncthreads();
    for (int yy = ty; yy < 32; yy += 8) {
        int n = n0 + yy, k = k0 + tx;
        if (n < N && k < K)
            WT[(size_t)(dstRowOff + n) * LK + dstColOff + k] = (f16)clampf(tile[tx][yy]);
    }
}

// BN on y; acc (f16, persistent) = (initAcc ? 0 : acc) + w * BN(y).  Vectorized x8.
__global__ void bn_apply(f16* __restrict__ y, const float* __restrict__ stats,
                         const float* __restrict__ g, const float* __restrict__ b,
                         float invN, float w, f16* __restrict__ acc, size_t total,
                         int initAcc) {
    size_t i = ((size_t)blockIdx.x * 256 + threadIdx.x) * 8;
    if (i >= total) return;
    int colb = (int)(i & 255);
    f16x8 yv = *(const f16x8*)(y + i);
    f16x8 av = {};
    if (!initAcc) av = *(const f16x8*)(acc + i);
    f16x8 yo, ao;
#pragma unroll
    for (int j = 0; j < 8; j++) {
        int col = colb + j;
        float m = stats[col] * invN;
        float var = stats[256 + col] * invN - m * m;
        if (var < 0.f) var = 0.f;
        float rs = 1.0f / sqrtf(var + 1e-5f);
        float v = ((float)yv[j] - m) * rs * g[col] + b[col];
        v = clampf(v);
        yo[j] = (f16)v;
        float p = initAcc ? 0.f : (float)av[j];
        ao[j] = (f16)clampf(p + w * v);
    }
    *(f16x8*)(y + i) = yo;
    *(f16x8*)(acc + i) = ao;
}

extern "C" void kernel_launch(void* const* d_in, const int* in_sizes, int n_in,
                              void* d_out, int out_size, void* d_ws, size_t ws_size,
                              hipStream_t stream) {
    char* ws = (char*)d_ws;
    size_t off = 0;
    auto alloc = [&](size_t bytes) -> void* {
        void* p = ws + off;
        off += (bytes + 255) & ~(size_t)255;
        return p;
    };

    // persistent (~46 MB)
    f16* gene_out = (f16*)alloc((size_t)N_G * 256 * 2);
    f16* dis_out  = (f16*)alloc((size_t)N_D * 256 * 2);
    f16* W1T = (f16*)alloc((size_t)2048 * 512 * 2);
    f16* W2T = (f16*)alloc((size_t)1024 * 2048 * 2);
    f16* W3T = (f16*)alloc((size_t)512 * 1024 * 2);
    f16* WcatT = (f16*)alloc((size_t)256 * 512 * 2);
    int* csr = (int*)alloc((size_t)E_G * 4);
    int* rowptr = (int*)alloc((size_t)(N_G + 1) * 4);
    int* cnt = (int*)alloc((size_t)N_G * 4);
    float* stats = (float*)alloc(512 * 4);

    char* scratch = ws + off;
    size_t avail = (ws_size > off) ? (ws_size - off) : 0;

    f16* ybA = (f16*)scratch;
    f16* ybB = ybA + (size_t)N_G * 256;
    f16* XAbuf = ybB + (size_t)N_G * 256;

    // head chunk: R rows use R*6144 bytes (h1 4KB + h2 2KB per row)
    int R = 32768;
    while ((size_t)R * 6144 > avail && R > 256) R >>= 1;
    int chunks = BATCH / R;
    f16* h1 = (f16*)scratch;
    f16* h2 = h1 + (size_t)R * 2048;

    const float* gene_x = (const float*)d_in[0];
    const float* disease_x = (const float*)d_in[1];
    const int* g_ei = (const int*)d_in[2];
    const int* d_ei = (const int*)d_in[3];
    const int* bidx = (const int*)d_in[4];
    float* out = (float*)d_out;

    const float wl[3] = {0.7f, 0.2f, 0.1f};

    auto run_tower = [&](const float* xin, const int* ei, int Nn, int E, int pbase, f16* tout) {
        size_t nelem = (size_t)Nn * 256;
        int nb8 = (int)((nelem / 8 + 255) / 256);
        cvt_f32_f16<<<nb8, 256, 0, stream>>>(xin, ybA, nelem);
        hipMemsetAsync(cnt, 0, (size_t)Nn * 4, stream);
        count_deg<<<(E + 255) / 256, 256, 0, stream>>>(ei, E, cnt);
        scan_deg<<<1, 1024, 0, stream>>>(cnt, rowptr, Nn);
        hipMemsetAsync(cnt, 0, (size_t)Nn * 4, stream);
        fill_csr<<<(E + 255) / 256, 256, 0, stream>>>(ei, E, rowptr, cnt, csr);
        f16* yin = ybA;
        f16* yout = ybB;
        int RB = (Nn + 127) / 128;
        int RBp = (RB + 7) & ~7;
        for (int l = 0; l < 3; l++) {
            const float* Wr = (const float*)d_in[pbase + l * 5 + 0];
            const float* br = (const float*)d_in[pbase + l * 5 + 1];
            const float* Wss = (const float*)d_in[pbase + l * 5 + 2];
            const float* bg = (const float*)d_in[pbase + l * 5 + 3];
            const float* bb = (const float*)d_in[pbase + l * 5 + 4];
            transpose_tile<<<dim3(8, 8), dim3(32, 8), 0, stream>>>(Wss, WcatT, 256, 256, 0, 0, 512);
            transpose_tile<<<dim3(8, 8), dim3(32, 8), 0, stream>>>(Wr, WcatT, 256, 256, 0, 256, 512);
            agg_x<<<(Nn * 64 + 255) / 256, 256, 0, stream>>>(rowptr, csr, yin, XAbuf, Nn);
            hipMemsetAsync(stats, 0, 512 * 4, stream);
            // y = lrelu([X|XA] @ [Ws;Wr] + br), fused column stats
            gemm_tower<<<2 * RBp, 256, 0, stream>>>(yin, XAbuf, WcatT, br, yout,
                                                    Nn, 256, 512, 2, RBp, stats);
            bn_apply<<<nb8, 256, 0, stream>>>(yout, stats, bg, bb, 1.0f / Nn, wl[l],
                                              tout, nelem, l == 0);
            f16* tmp = yin; yin = yout; yout = tmp;
        }
    };

    run_tower(gene_x, g_ei, N_G, E_G, 5, gene_out);
    run_tower(disease_x, d_ei, N_D, E_D, 20, dis_out);

    const float* lin1_W = (const float*)d_in[35];
    const float* lin1_b = (const float*)d_in[36];
    const float* lin2_W = (const float*)d_in[37];
    const float* lin2_b = (const float*)d_in[38];
    const float* lin3_W = (const float*)d_in[39];
    const float* lin3_b = (const float*)d_in[40];
    const float* lin4_W = (const float*)d_in[41];
    const float* lin4_b = (const float*)d_in[42];

    transpose_tile<<<dim3(64, 16), dim3(32, 8), 0, stream>>>(lin1_W, W1T, 512, 2048, 0, 0, 512);
    transpose_tile<<<dim3(32, 64), dim3(32, 8), 0, stream>>>(lin2_W, W2T, 2048, 1024, 0, 0, 2048);
    transpose_tile<<<dim3(16, 32), dim3(32, 8), 0, stream>>>(lin3_W, W3T, 1024, 512, 0, 0, 1024);
    init_out<<<(BATCH * 2 + 255) / 256, 256, 0, stream>>>(lin4_b, out, BATCH * 2);

    for (int c = 0; c < chunks; c++) {
        int rb = c * R;
        int RB = R / 128;
        if ((R & 255) == 0) {
            // lin1 (gather) on the 256x256 prefetch-2 kernel — best measured for gather
            int RB2 = R / 256;
            gemm256<<<8 * RB2, 512, 0, stream>>>(nullptr, bidx, gene_out, dis_out, rb,
                                                 W1T, lin1_b, h1, R, 2048, 512, 1, 8, RB2);
        } else {
            gemm_f16<<<16 * RB, 256, 0, stream>>>(nullptr, bidx, gene_out, dis_out, rb,
                                                  W1T, lin1_b, h1, R, 2048, 512, 1, 16, RB,
                                                  nullptr, nullptr);
        }
        // lin2 on the 128x128 84-VGPR kernel — best measured for L2-resident A
        gemm_f16<<<8 * RB, 256, 0, stream>>>(h1, nullptr, nullptr, nullptr, 0,
                                             W2T, lin2_b, h2, R, 1024, 2048, 1, 8, RB,
                                             nullptr, nullptr);
        // lin3 with fused lin4: atomics into out (fp32)
        gemm_f16<<<4 * RB, 256, 0, stream>>>(h2, nullptr, nullptr, nullptr, rb,
                                             W3T, lin3_b, nullptr, R, 512, 1024, 1, 4, RB,
                                             lin4_W, out);
    }
}

// Round 10
// 1524.187 us; speedup vs baseline: 1.0542x; 1.0214x over previous
//
#include <hip/hip_runtime.h>
#include <hip/hip_bf16.h>
#include <cstdint>
#include <cstddef>

#define N_G 50000
#define N_D 20000
#define E_G 300000
#define E_D 150000
#define BATCH 65536

typedef _Float16 f16;
typedef _Float16 f16x8 __attribute__((ext_vector_type(8)));
typedef _Float16 f16x4 __attribute__((ext_vector_type(4)));
typedef float f32x4 __attribute__((ext_vector_type(4)));

__device__ __forceinline__ float clampf(float v) {
    return fminf(fmaxf(v, -60000.f), 60000.f);  // also squashes NaN
}

__device__ __forceinline__ void gl_lds16(const void* g, void* l) {
    __builtin_amdgcn_global_load_lds(
        (const __attribute__((address_space(1))) unsigned int*)g,
        (__attribute__((address_space(3))) unsigned int*)l, 16, 0, 0);
}

// ---------------- GEMM (128x128, 4 waves): C = act(A @ Bt^T + bias) ----------------
// Pure 84-VGPR form (R15-verified). lin2 / lin3(+lin4) / A-B lin1-gather.
__global__ __launch_bounds__(256) void gemm_f16(
    const f16* __restrict__ A,
    const int* __restrict__ bidx,
    const f16* __restrict__ geneT, const f16* __restrict__ disT, int rowBase,
    const f16* __restrict__ Bt, const float* __restrict__ bias,
    f16* __restrict__ C, int M, int N, int K, int relu, int CB, int RB,
    const float* __restrict__ W4, float* __restrict__ outF)
{
    alignas(16) __shared__ f16 sA[128 * 64];
    alignas(16) __shared__ f16 sB[128 * 64];
    const int t = threadIdx.x;
    const int w = t >> 6, l = t & 63;
    const int wm = w >> 1, wn = w & 1;
    const int q = l >> 4, lr = l & 15;

    int flat = blockIdx.x;
    int cb, rb;
    if ((RB & 7) == 0) {
        int x = flat & 7, idx = flat >> 3;
        int Sx = RB >> 3;
        cb = idx % CB;
        rb = x * Sx + idx / CB;
    } else {
        cb = flat % CB;
        rb = flat / CB;
    }
    const int mBase = rb * 128, nBase = cb * 128;

    const int subrow = l >> 3;   // 0..7
    const int c = l & 7;         // 16B chunk 0..7 within a 128B row
    const char* pA[4];
    const char* pD[4];
    const char* pB[4];
    const bool fused = (bidx != nullptr);
    const bool concat = (!fused && disT != nullptr);
    const bool twoSrc = fused || concat;
#pragma unroll
    for (int j = 0; j < 4; j++) {
        int seg = j * 4 + w;
        int lrow = seg * 8 + subrow;               // 0..127
        int coff = ((c ^ (lrow & 7)) << 4);        // swizzled chunk byte offset
        if (fused) {
            int rg = rowBase + mBase + lrow;       // M % 128 == 0 on this path
            int gi = bidx[2 * rg], di = bidx[2 * rg + 1];
            pA[j] = (const char*)geneT + (size_t)gi * 512 + coff;
            pD[j] = (const char*)disT + (size_t)di * 512 + coff;
        } else if (concat) {
            int arow = mBase + lrow; if (arow > M - 1) arow = M - 1;
            pA[j] = (const char*)geneT + (size_t)arow * 512 + coff;
            pD[j] = (const char*)disT + (size_t)arow * 512 + coff;
        } else {
            int arow = mBase + lrow; if (arow > M - 1) arow = M - 1;
            pA[j] = (const char*)A + (size_t)arow * K * 2 + coff;
            pD[j] = nullptr;
        }
        int brow = nBase + lrow; if (brow > N - 1) brow = N - 1;
        pB[j] = (const char*)Bt + (size_t)brow * K * 2 + coff;
    }

    f32x4 acc[4][4] = {};

    for (int k0 = 0; k0 < K; k0 += 64) {
        __syncthreads();
#pragma unroll
        for (int j = 0; j < 4; j++) {
            int seg = j * 4 + w;
            const char* srcA;
            if (twoSrc)
                srcA = (k0 < 256) ? (pA[j] + (size_t)k0 * 2) : (pD[j] + (size_t)(k0 - 256) * 2);
            else
                srcA = pA[j] + (size_t)k0 * 2;
            gl_lds16(srcA, sA + seg * 512);
            gl_lds16(pB[j] + (size_t)k0 * 2, sB + seg * 512);
        }
        __syncthreads();
        f16x8 a0[4], a1[4], b0[4], b1[4];
#pragma unroll
        for (int i = 0; i < 4; i++) {
            int r = wm * 64 + i * 16 + lr;
            int rs = r * 64;
            int x0 = (q ^ (r & 7)) << 3;
            int x1 = ((4 + q) ^ (r & 7)) << 3;
            a0[i] = *(const f16x8*)(sA + rs + x0);
            a1[i] = *(const f16x8*)(sA + rs + x1);
        }
#pragma unroll
        for (int jj = 0; jj < 4; jj++) {
            int r = wn * 64 + jj * 16 + lr;
            int rs = r * 64;
            int x0 = (q ^ (r & 7)) << 3;
            int x1 = ((4 + q) ^ (r & 7)) << 3;
            b0[jj] = *(const f16x8*)(sB + rs + x0);
            b1[jj] = *(const f16x8*)(sB + rs + x1);
        }
#pragma unroll
        for (int i = 0; i < 4; i++)
#pragma unroll
            for (int jj = 0; jj < 4; jj++) {
                acc[i][jj] = __builtin_amdgcn_mfma_f32_16x16x32_f16(a0[i], b0[jj], acc[i][jj], 0, 0, 0);
                acc[i][jj] = __builtin_amdgcn_mfma_f32_16x16x32_f16(a1[i], b1[jj], acc[i][jj], 0, 0, 0);
            }
    }

    if (W4 != nullptr) {
        // fused final linear: out[rowBase+row] += lrelu(acc + bias) @ W4 (512x2)
        float w40[4], w41[4];
#pragma unroll
        for (int j = 0; j < 4; j++) {
            int col = nBase + wn * 64 + j * 16 + lr;
            w40[j] = W4[col * 2];
            w41[j] = W4[col * 2 + 1];
        }
#pragma unroll
        for (int i = 0; i < 4; i++) {
#pragma unroll
            for (int r = 0; r < 4; r++) {
                int row = mBase + wm * 64 + i * 16 + q * 4 + r;
                float s0 = 0.f, s1 = 0.f;
#pragma unroll
                for (int j = 0; j < 4; j++) {
                    int col = nBase + wn * 64 + j * 16 + lr;
                    float v = acc[i][j][r] + bias[col];
                    v = v >= 0.f ? v : 0.01f * v;
                    v = clampf(v);
                    s0 += v * w40[j];
                    s1 += v * w41[j];
                }
#pragma unroll
                for (int off = 1; off < 16; off <<= 1) {
                    s0 += __shfl_xor(s0, off);
                    s1 += __shfl_xor(s1, off);
                }
                if (lr == 0 && row < M) {
                    atomicAdd(&outF[(size_t)(rowBase + row) * 2], s0);
                    atomicAdd(&outF[(size_t)(rowBase + row) * 2 + 1], s1);
                }
            }
        }
        return;
    }

    // ---- epilogue: per-wave LDS transpose, then coalesced f16x8 stores ----
    __syncthreads();
    f16* lt = ((w >> 1) ? sB : sA) + (w & 1) * 4096;

    float bj[4];
#pragma unroll
    for (int j = 0; j < 4; j++)
        bj[j] = bias ? bias[nBase + wn * 64 + j * 16 + lr] : 0.f;

#pragma unroll
    for (int i = 0; i < 4; i++)
#pragma unroll
        for (int j = 0; j < 4; j++) {
            int col = j * 16 + lr;
#pragma unroll
            for (int r = 0; r < 4; r++) {
                int row = i * 16 + q * 4 + r;       // 0..63 wave-local
                float v = acc[i][j][r] + bj[j];
                if (relu) v = v >= 0.f ? v : 0.01f * v;
                v = clampf(v);
                int cs = col ^ ((((row >> 2) & 3) << 4) ^ ((row & 3) << 3));
                lt[row * 64 + cs] = (f16)v;
            }
        }
    __syncthreads();

    const int rr = l >> 3;
    const int c8 = l & 7;
#pragma unroll
    for (int it = 0; it < 8; it++) {
        int row = it * 8 + rr;
        int cs = (c8 * 8) ^ ((((row >> 2) & 3) << 4) ^ ((row & 3) << 3));
        f16x8 vv = *(const f16x8*)(lt + row * 64 + cs);
        int grow = mBase + wm * 64 + row;
        if (grow < M)
            *(f16x8*)(C + (size_t)grow * N + nBase + wn * 64 + c8 * 8) = vv;
    }
}

// ---------------- GEMM 256x256, 8 waves, prefetch-distance-2 (R11-verified) ---------
__global__ __launch_bounds__(512) void gemm256(
    const f16* __restrict__ A,
    const int* __restrict__ bidx,
    const f16* __restrict__ geneT, const f16* __restrict__ disT, int rowBase,
    const f16* __restrict__ Bt, const float* __restrict__ bias,
    f16* __restrict__ C, int M, int N, int K, int relu, int CB, int RB)
{
    alignas(16) __shared__ f16 sm[81920];   // A: 3x16384 | B: 2x16384 (f16 units)
    const int t = threadIdx.x;
    const int w = t >> 6, l = t & 63;
    const int wm = w >> 2, wn = w & 3;      // 2 x 4 wave grid
    const int q = l >> 4, lr = l & 15;

    int flat = blockIdx.x;
    int cb, rb;
    if ((RB & 7) == 0) {
        int x = flat & 7, idx = flat >> 3;
        int Sx = RB >> 3;
        cb = idx % CB;
        rb = x * Sx + idx / CB;
    } else {
        cb = flat % CB;
        rb = flat / CB;
    }
    const int mBase = rb * 256, nBase = cb * 256;

    const int subrow = l >> 3;   // 0..7
    const int c = l & 7;         // 16B chunk within a 128B row
    const bool gat = (bidx != nullptr);
    const char* pA[4];
    const char* pD[4];
    const char* pB[4];
#pragma unroll
    for (int jj = 0; jj < 4; jj++) {
        int arow = jj * 64 + w * 8 + subrow;        // 0..255 tile-local row
        int coff = ((c ^ (arow & 7)) << 4);         // inverse-swizzled source chunk
        if (gat) {
            int rg = rowBase + mBase + arow;        // M % 256 == 0 on this path
            int gi = bidx[2 * rg], di = bidx[2 * rg + 1];
            pA[jj] = (const char*)geneT + (size_t)gi * 512 + coff;
            pD[jj] = (const char*)disT + (size_t)di * 512 + coff;
        } else {
            int ga = mBase + arow; if (ga > M - 1) ga = M - 1;
            pA[jj] = (const char*)A + (size_t)ga * K * 2 + coff;
            pD[jj] = nullptr;
        }
        int gb = nBase + arow; if (gb > N - 1) gb = N - 1;
        pB[jj] = (const char*)Bt + (size_t)gb * K * 2 + coff;
    }

    f16* const smA = sm;                // 3 bufs
    f16* const smB = sm + 3 * 16384;    // 2 bufs

    auto stageA = [&](int abuf, int k0) {
        f16* bA = smA + abuf * 16384;
#pragma unroll
        for (int jj = 0; jj < 4; jj++) {
            int R0 = jj * 64 + w * 8;               // wave-uniform LDS row base
            const char* srcA;
            if (gat)
                srcA = (k0 < 256) ? (pA[jj] + (size_t)k0 * 2) : (pD[jj] + (size_t)(k0 - 256) * 2);
            else
                srcA = pA[jj] + (size_t)k0 * 2;
            gl_lds16(srcA, bA + R0 * 64);
        }
    };
    auto stageB = [&](int bbuf, int k0) {
        f16* bB = smB + bbuf * 16384;
#pragma unroll
        for (int jj = 0; jj < 4; jj++) {
            int R0 = jj * 64 + w * 8;
            gl_lds16(pB[jj] + (size_t)k0 * 2, bB + R0 * 64);
        }
    };

    f32x4 acc[8][4] = {};
    const int nkt = K >> 6;

    // prologue: A(0), B(0), A(1)
    stageA(0, 0);
    stageB(0, 0);
    if (nkt > 1) stageA(1, 64);

    for (int kt = 0; kt < nkt; kt++) {
        if (kt + 1 < nkt) stageB((kt + 1) & 1, (kt + 1) << 6);
        if (kt + 2 < nkt) stageA((kt + 2) % 3, (kt + 2) << 6);
        if (kt + 2 < nkt)      asm volatile("s_waitcnt vmcnt(12)" ::: "memory");
        else if (kt + 1 < nkt) asm volatile("s_waitcnt vmcnt(8)" ::: "memory");
        else                   asm volatile("s_waitcnt vmcnt(0)" ::: "memory");
        __builtin_amdgcn_s_barrier();
        __builtin_amdgcn_sched_barrier(0);
        const f16* bA = smA + (kt % 3) * 16384;
        const f16* bB = smB + (kt & 1) * 16384;
#pragma unroll
        for (int ks = 0; ks < 2; ks++) {
            f16x8 bf[4];
#pragma unroll
            for (int nf = 0; nf < 4; nf++) {
                int rB = wn * 64 + nf * 16 + lr;
                bf[nf] = *(const f16x8*)(bB + rB * 64 + ((((ks << 2) + q) ^ (rB & 7)) << 3));
            }
#pragma unroll
            for (int mf = 0; mf < 8; mf++) {
                int rA = wm * 128 + mf * 16 + lr;
                f16x8 af = *(const f16x8*)(bA + rA * 64 + ((((ks << 2) + q) ^ (rA & 7)) << 3));
#pragma unroll
                for (int nf = 0; nf < 4; nf++)
                    acc[mf][nf] = __builtin_amdgcn_mfma_f32_16x16x32_f16(af, bf[nf], acc[mf][nf], 0, 0, 0);
            }
        }
        __builtin_amdgcn_sched_barrier(0);
        __builtin_amdgcn_s_barrier();
    }
    __builtin_amdgcn_sched_barrier(0);

    // ---- epilogue: per-wave 128x64 LDS transpose (16KB slice), f16x8 stores ----
    f16* lt = sm + w * 8192;
    float bj[4];
#pragma unroll
    for (int nf = 0; nf < 4; nf++)
        bj[nf] = bias ? bias[nBase + wn * 64 + nf * 16 + lr] : 0.f;

#pragma unroll
    for (int mf = 0; mf < 8; mf++)
#pragma unroll
        for (int nf = 0; nf < 4; nf++) {
            int col = nf * 16 + lr;
#pragma unroll
            for (int r = 0; r < 4; r++) {
                int row = mf * 16 + q * 4 + r;      // 0..127 wave-local
                float v = acc[mf][nf][r] + bj[nf];
                if (relu) v = v >= 0.f ? v : 0.01f * v;
                v = clampf(v);
                int cs = col ^ ((((row >> 2) & 3) << 4) ^ ((row & 3) << 3));
                lt[row * 64 + cs] = (f16)v;
            }
        }

    const int rr = l >> 3;
    const int c8 = l & 7;
#pragma unroll
    for (int it = 0; it < 16; it++) {
        int row = it * 8 + rr;                      // 0..127 wave-local
        int cs = (c8 * 8) ^ ((((row >> 2) & 3) << 4) ^ ((row & 3) << 3));
        f16x8 vv = *(const f16x8*)(lt + row * 64 + cs);
        int grow = mBase + wm * 128 + row;
        if (grow < M)
            *(f16x8*)(C + (size_t)grow * N + nBase + wn * 64 + c8 * 8) = vv;
    }
}

// ---------------- tower GEMM (concat staging + fused column-stats) ----
// y = lrelu([X|XA] @ Bt^T + bias); stats[0..255]=sum, [256..511]=sumsq (for BN).
__global__ __launch_bounds__(256) void gemm_tower(
    const f16* __restrict__ X, const f16* __restrict__ XA,
    const f16* __restrict__ Bt, const float* __restrict__ bias,
    f16* __restrict__ C, int M, int N, int K, int CB, int RB,
    float* __restrict__ stats)
{
    alignas(16) __shared__ f16 sA[128 * 64];
    alignas(16) __shared__ f16 sB[128 * 64];
    const int t = threadIdx.x;
    const int w = t >> 6, l = t & 63;
    const int wm = w >> 1, wn = w & 1;
    const int q = l >> 4, lr = l & 15;

    int flat = blockIdx.x;
    int cb, rb;
    if ((RB & 7) == 0) {
        int x = flat & 7, idx = flat >> 3;
        int Sx = RB >> 3;
        cb = idx % CB;
        rb = x * Sx + idx / CB;
    } else {
        cb = flat % CB;
        rb = flat / CB;
    }
    const int mBase = rb * 128, nBase = cb * 128;

    const int subrow = l >> 3;
    const int c = l & 7;
    const char* pA[4];
    const char* pD[4];
    const char* pB[4];
#pragma unroll
    for (int j = 0; j < 4; j++) {
        int seg = j * 4 + w;
        int lrow = seg * 8 + subrow;
        int coff = ((c ^ (lrow & 7)) << 4);
        int arow = mBase + lrow; if (arow > M - 1) arow = M - 1;
        pA[j] = (const char*)X + (size_t)arow * 512 + coff;
        pD[j] = (const char*)XA + (size_t)arow * 512 + coff;
        int brow = nBase + lrow; if (brow > N - 1) brow = N - 1;
        pB[j] = (const char*)Bt + (size_t)brow * K * 2 + coff;
    }

    f32x4 acc[4][4] = {};

    for (int k0 = 0; k0 < K; k0 += 64) {
        __syncthreads();
#pragma unroll
        for (int j = 0; j < 4; j++) {
            int seg = j * 4 + w;
            const char* srcA = (k0 < 256) ? (pA[j] + (size_t)k0 * 2)
                                          : (pD[j] + (size_t)(k0 - 256) * 2);
            gl_lds16(srcA, sA + seg * 512);
            gl_lds16(pB[j] + (size_t)k0 * 2, sB + seg * 512);
        }
        __syncthreads();
        f16x8 a0[4], a1[4], b0[4], b1[4];
#pragma unroll
        for (int i = 0; i < 4; i++) {
            int r = wm * 64 + i * 16 + lr;
            int rs = r * 64;
            int x0 = (q ^ (r & 7)) << 3;
            int x1 = ((4 + q) ^ (r & 7)) << 3;
            a0[i] = *(const f16x8*)(sA + rs + x0);
            a1[i] = *(const f16x8*)(sA + rs + x1);
        }
#pragma unroll
        for (int jj = 0; jj < 4; jj++) {
            int r = wn * 64 + jj * 16 + lr;
            int rs = r * 64;
            int x0 = (q ^ (r & 7)) << 3;
            int x1 = ((4 + q) ^ (r & 7)) << 3;
            b0[jj] = *(const f16x8*)(sB + rs + x0);
            b1[jj] = *(const f16x8*)(sB + rs + x1);
        }
#pragma unroll
        for (int i = 0; i < 4; i++)
#pragma unroll
            for (int jj = 0; jj < 4; jj++) {
                acc[i][jj] = __builtin_amdgcn_mfma_f32_16x16x32_f16(a0[i], b0[jj], acc[i][jj], 0, 0, 0);
                acc[i][jj] = __builtin_amdgcn_mfma_f32_16x16x32_f16(a1[i], b1[jj], acc[i][jj], 0, 0, 0);
            }
    }

    // ---- epilogue: bias, lrelu, fused stats, LDS transpose, store ----
    __syncthreads();
    f16* lt = ((w >> 1) ? sB : sA) + (w & 1) * 4096;

    float bj[4];
#pragma unroll
    for (int j = 0; j < 4; j++)
        bj[j] = bias[nBase + wn * 64 + j * 16 + lr];

    float sj[4] = {0.f, 0.f, 0.f, 0.f}, s2j[4] = {0.f, 0.f, 0.f, 0.f};
#pragma unroll
    for (int i = 0; i < 4; i++)
#pragma unroll
        for (int j = 0; j < 4; j++) {
            int col = j * 16 + lr;
#pragma unroll
            for (int r = 0; r < 4; r++) {
                int row = i * 16 + q * 4 + r;
                float v = acc[i][j][r] + bj[j];
                v = v >= 0.f ? v : 0.01f * v;
                v = clampf(v);
                if ((mBase + wm * 64 + row) < M) { sj[j] += v; s2j[j] += v * v; }
                int cs = col ^ ((((row >> 2) & 3) << 4) ^ ((row & 3) << 3));
                lt[row * 64 + cs] = (f16)v;
            }
        }

    // reduce over q (lanes ^16, ^32 share lr), one atomic pair per column per wave
#pragma unroll
    for (int j = 0; j < 4; j++) {
        float s = sj[j], s2 = s2j[j];
        s += __shfl_xor(s, 16); s2 += __shfl_xor(s2, 16);
        s += __shfl_xor(s, 32); s2 += __shfl_xor(s2, 32);
        if (q == 0) {
            int col = nBase + wn * 64 + j * 16 + lr;
            if (col < N) {
                atomicAdd(&stats[col], s);
                atomicAdd(&stats[256 + col], s2);
            }
        }
    }
    __syncthreads();

    const int rr = l >> 3;
    const int c8 = l & 7;
#pragma unroll
    for (int it = 0; it < 8; it++) {
        int row = it * 8 + rr;
        int cs = (c8 * 8) ^ ((((row >> 2) & 3) << 4) ^ ((row & 3) << 3));
        f16x8 vv = *(const f16x8*)(lt + row * 64 + cs);
        int grow = mBase + wm * 64 + row;
        if (grow < M)
            *(f16x8*)(C + (size_t)grow * N + nBase + wn * 64 + c8 * 8) = vv;
    }
}

// ---------------- small kernels ----------------
__global__ void cvt_f32_f16(const float* __restrict__ in, f16* __restrict__ out, size_t n) {
    size_t i = ((size_t)blockIdx.x * 256 + threadIdx.x) * 8;
    if (i >= n) return;
    f32x4 a = *(const f32x4*)(in + i);
    f32x4 b = *(const f32x4*)(in + i + 4);
    f16x8 o;
    o[0] = (f16)clampf(a.x); o[1] = (f16)clampf(a.y);
    o[2] = (f16)clampf(a.z); o[3] = (f16)clampf(a.w);
    o[4] = (f16)clampf(b.x); o[5] = (f16)clampf(b.y);
    o[6] = (f16)clampf(b.z); o[7] = (f16)clampf(b.w);
    *(f16x8*)(out + i) = o;
}

__global__ void init_out(const float* __restrict__ b4, float* __restrict__ out, int n) {
    int i = blockIdx.x * 256 + threadIdx.x;
    if (i < n) out[i] = b4[i & 1];
}

__global__ void count_deg(const int* __restrict__ ei, int E, int* __restrict__ deg) {
    int e = blockIdx.x * 256 + threadIdx.x;
    if (e < E) atomicAdd(&deg[ei[E + e]], 1);
}

__global__ void scan_deg(const int* __restrict__ deg, int* __restrict__ rowptr, int Nn) {
    __shared__ int part[1024];
    const int t = threadIdx.x;
    const int C = (Nn + 1023) >> 10;
    const int base = t * C;
    int s = 0;
    for (int i = 0; i < C; i++) { int idx = base + i; if (idx < Nn) s += deg[idx]; }
    part[t] = s;
    __syncthreads();
    for (int off = 1; off < 1024; off <<= 1) {
        int v = (t >= off) ? part[t - off] : 0;
        __syncthreads();
        part[t] += v;
        __syncthreads();
    }
    int pre = (t == 0) ? 0 : part[t - 1];
    for (int i = 0; i < C; i++) {
        int idx = base + i;
        if (idx < Nn) { rowptr[idx] = pre; pre += deg[idx]; }
    }
    if (t == 1023) rowptr[Nn] = part[1023];
}

__global__ void fill_csr(const int* __restrict__ ei, int E, const int* __restrict__ rowptr,
                         int* __restrict__ cursor, int* __restrict__ csr) {
    int e = blockIdx.x * 256 + threadIdx.x;
    if (e < E) {
        int d = ei[E + e];
        int p = rowptr[d] + atomicAdd(&cursor[d], 1);
        csr[p] = ei[e];
    }
}

// pre-aggregation (GraphConv linearity): XA[i] = sum_{j->i} X[j]
__global__ void agg_x(const int* __restrict__ rowptr, const int* __restrict__ csr,
                      const f16* __restrict__ X, f16* __restrict__ XA, int Nn) {
    int gid = blockIdx.x * 256 + threadIdx.x;
    int node = gid >> 6, l = gid & 63;
    if (node >= Nn) return;
    int beg = rowptr[node], end = rowptr[node + 1];
    float s0 = 0.f, s1 = 0.f, s2 = 0.f, s3 = 0.f;
    for (int e = beg; e < end; e++) {
        int src = csr[e];
        f16x4 xv = *(const f16x4*)(X + (size_t)src * 256 + l * 4);
        s0 += (float)xv.x; s1 += (float)xv.y; s2 += (float)xv.z; s3 += (float)xv.w;
    }
    f16x4 o;
    o.x = (f16)clampf(s0); o.y = (f16)clampf(s1);
    o.z = (f16)clampf(s2); o.w = (f16)clampf(s3);
    *(f16x4*)(XA + (size_t)node * 256 + l * 4) = o;
}

// Tiled transpose: WT[(dstRowOff+n)*LK + dstColOff + k] = W[k][n]
__global__ void transpose_tile(const float* __restrict__ W, f16* __restrict__ WT,
                               int K, int N, int dstRowOff, int dstColOff, int LK) {
    __shared__ float tile[32][33];
    int n0 = blockIdx.x * 32, k0 = blockIdx.y * 32;
    int tx = threadIdx.x, ty = threadIdx.y;
    for (int yy = ty; yy < 32; yy += 8) {
        int k = k0 + yy, n = n0 + tx;
        tile[yy][tx] = (k < K && n < N) ? W[(size_t)k * N + n] : 0.f;
    }
    __syncthreads();
    for (int yy = ty; yy < 32; yy += 8) {
        int n = n0 + yy, k = k0 + tx;
        if (n < N && k < K)
            WT[(size_t)(dstRowOff + n) * LK + dstColOff + k] = (f16)clampf(tile[tx][yy]);
    }
}

// R17: both tower-layer weight transposes in ONE launch (grid.z picks Ws->cols 0-255,
// Wr->cols 256-511). Hardcoded 256x256 each, WcatT rows of length 512.
__global__ void transpose_pair(const float* __restrict__ Ws, const float* __restrict__ Wr,
                               f16* __restrict__ WT) {
    __shared__ float tile[32][33];
    const float* W = blockIdx.z ? Wr : Ws;
    const int colOff = blockIdx.z ? 256 : 0;
    int n0 = blockIdx.x * 32, k0 = blockIdx.y * 32;
    int tx = threadIdx.x, ty = threadIdx.y;
    for (int yy = ty; yy < 32; yy += 8)
        tile[yy][tx] = W[(size_t)(k0 + yy) * 256 + n0 + tx];
    __syncthreads();
    for (int yy = ty; yy < 32; yy += 8)
        WT[(size_t)(n0 + yy) * 512 + colOff + k0 + tx] = (f16)clampf(tile[tx][yy]);
}

// BN on y; acc (f16, persistent) = (initAcc ? 0 : acc) + w * BN(y).  Vectorized x8.
__global__ void bn_apply(f16* __restrict__ y, const float* __restrict__ stats,
                         const float* __restrict__ g, const float* __restrict__ b,
                         float invN, float w, f16* __restrict__ acc, size_t total,
                         int initAcc) {
    size_t i = ((size_t)blockIdx.x * 256 + threadIdx.x) * 8;
    if (i >= total) return;
    int colb = (int)(i & 255);
    f16x8 yv = *(const f16x8*)(y + i);
    f16x8 av = {};
    if (!initAcc) av = *(const f16x8*)(acc + i);
    f16x8 yo, ao;
#pragma unroll
    for (int j = 0; j < 8; j++) {
        int col = colb + j;
        float m = stats[col] * invN;
        float var = stats[256 + col] * invN - m * m;
        if (var < 0.f) var = 0.f;
        float rs = 1.0f / sqrtf(var + 1e-5f);
        float v = ((float)yv[j] - m) * rs * g[col] + b[col];
        v = clampf(v);
        yo[j] = (f16)v;
        float p = initAcc ? 0.f : (float)av[j];
        ao[j] = (f16)clampf(p + w * v);
    }
    *(f16x8*)(y + i) = yo;
    *(f16x8*)(acc + i) = ao;
}

extern "C" void kernel_launch(void* const* d_in, const int* in_sizes, int n_in,
                              void* d_out, int out_size, void* d_ws, size_t ws_size,
                              hipStream_t stream) {
    char* ws = (char*)d_ws;
    size_t off = 0;
    auto alloc = [&](size_t bytes) -> void* {
        void* p = ws + off;
        off += (bytes + 255) & ~(size_t)255;
        return p;
    };

    // persistent (~46 MB)
    f16* gene_out = (f16*)alloc((size_t)N_G * 256 * 2);
    f16* dis_out  = (f16*)alloc((size_t)N_D * 256 * 2);
    f16* W1T = (f16*)alloc((size_t)2048 * 512 * 2);
    f16* W2T = (f16*)alloc((size_t)1024 * 2048 * 2);
    f16* W3T = (f16*)alloc((size_t)512 * 1024 * 2);
    f16* WcatT = (f16*)alloc((size_t)256 * 512 * 2);
    int* csr = (int*)alloc((size_t)E_G * 4);
    int* rowptr = (int*)alloc((size_t)(N_G + 1) * 4);
    int* cnt = (int*)alloc((size_t)N_G * 4);
    float* statsAll = (float*)alloc(6 * 512 * 4);   // (tower,layer) slices, zeroed once

    char* scratch = ws + off;
    size_t avail = (ws_size > off) ? (ws_size - off) : 0;

    f16* ybA = (f16*)scratch;
    f16* ybB = ybA + (size_t)N_G * 256;
    f16* XAbuf = ybB + (size_t)N_G * 256;

    // head chunk: R rows use R*6144 bytes (h1 4KB + h2 2KB per row)
    int R = 32768;
    while ((size_t)R * 6144 > avail && R > 256) R >>= 1;
    int chunks = BATCH / R;
    f16* h1 = (f16*)scratch;
    f16* h2 = h1 + (size_t)R * 2048;

    const float* gene_x = (const float*)d_in[0];
    const float* disease_x = (const float*)d_in[1];
    const int* g_ei = (const int*)d_in[2];
    const int* d_ei = (const int*)d_in[3];
    const int* bidx = (const int*)d_in[4];
    float* out = (float*)d_out;

    const float wl[3] = {0.7f, 0.2f, 0.1f};

    // zero all 6 stats slices once (R17: was 6 per-layer memsets in the serial chain)
    hipMemsetAsync(statsAll, 0, 6 * 512 * 4, stream);

    auto run_tower = [&](const float* xin, const int* ei, int Nn, int E, int pbase,
                         f16* tout, float* statsBase) {
        size_t nelem = (size_t)Nn * 256;
        int nb8 = (int)((nelem / 8 + 255) / 256);
        cvt_f32_f16<<<nb8, 256, 0, stream>>>(xin, ybA, nelem);
        hipMemsetAsync(cnt, 0, (size_t)Nn * 4, stream);
        count_deg<<<(E + 255) / 256, 256, 0, stream>>>(ei, E, cnt);
        scan_deg<<<1, 1024, 0, stream>>>(cnt, rowptr, Nn);
        hipMemsetAsync(cnt, 0, (size_t)Nn * 4, stream);
        fill_csr<<<(E + 255) / 256, 256, 0, stream>>>(ei, E, rowptr, cnt, csr);
        f16* yin = ybA;
        f16* yout = ybB;
        int RB = (Nn + 127) / 128;
        int RBp = (RB + 7) & ~7;
        for (int l = 0; l < 3; l++) {
            const float* Wr = (const float*)d_in[pbase + l * 5 + 0];
            const float* br = (const float*)d_in[pbase + l * 5 + 1];
            const float* Wss = (const float*)d_in[pbase + l * 5 + 2];
            const float* bg = (const float*)d_in[pbase + l * 5 + 3];
            const float* bb = (const float*)d_in[pbase + l * 5 + 4];
            transpose_pair<<<dim3(8, 8, 2), dim3(32, 8), 0, stream>>>(Wss, Wr, WcatT);
            agg_x<<<(Nn * 64 + 255) / 256, 256, 0, stream>>>(rowptr, csr, yin, XAbuf, Nn);
            float* stats = statsBase + l * 512;
            // y = lrelu([X|XA] @ [Ws;Wr] + br), fused column stats
            gemm_tower<<<2 * RBp, 256, 0, stream>>>(yin, XAbuf, WcatT, br, yout,
                                                    Nn, 256, 512, 2, RBp, stats);
            bn_apply<<<nb8, 256, 0, stream>>>(yout, stats, bg, bb, 1.0f / Nn, wl[l],
                                              tout, nelem, l == 0);
            f16* tmp = yin; yin = yout; yout = tmp;
        }
    };

    run_tower(gene_x, g_ei, N_G, E_G, 5, gene_out, statsAll);
    run_tower(disease_x, d_ei, N_D, E_D, 20, dis_out, statsAll + 3 * 512);

    const float* lin1_W = (const float*)d_in[35];
    const float* lin1_b = (const float*)d_in[36];
    const float* lin2_W = (const float*)d_in[37];
    const float* lin2_b = (const float*)d_in[38];
    const float* lin3_W = (const float*)d_in[39];
    const float* lin3_b = (const float*)d_in[40];
    const float* lin4_W = (const float*)d_in[41];
    const float* lin4_b = (const float*)d_in[42];

    transpose_tile<<<dim3(64, 16), dim3(32, 8), 0, stream>>>(lin1_W, W1T, 512, 2048, 0, 0, 512);
    transpose_tile<<<dim3(32, 64), dim3(32, 8), 0, stream>>>(lin2_W, W2T, 2048, 1024, 0, 0, 2048);
    transpose_tile<<<dim3(16, 32), dim3(32, 8), 0, stream>>>(lin3_W, W3T, 1024, 512, 0, 0, 1024);
    init_out<<<(BATCH * 2 + 255) / 256, 256, 0, stream>>>(lin4_b, out, BATCH * 2);

    // R17 within-run A/B (cross-round totals have +-50-100us machine noise):
    //   lin1: chunk0 -> gemm256 (tripbuf), chunk1 -> gemm_f16 (128^2 gather)
    //   lin2: chunk0 -> gemm_f16 (128^2),  chunk1 -> gemm256 (tripbuf)
    // Distinguish in counters by name + WRITE_SIZE (lin1 writes 131072 KB, lin2 65536).
    for (int c = 0; c < chunks; c++) {
        int rb = c * R;
        int RB = R / 128;
        int RB2 = R / 256;
        bool big1 = (c == 0) && ((R & 255) == 0);
        bool big2 = (c == 1) && ((R & 255) == 0);
        if (big1)
            gemm256<<<8 * RB2, 512, 0, stream>>>(nullptr, bidx, gene_out, dis_out, rb,
                                                 W1T, lin1_b, h1, R, 2048, 512, 1, 8, RB2);
        else
            gemm_f16<<<16 * RB, 256, 0, stream>>>(nullptr, bidx, gene_out, dis_out, rb,
                                                  W1T, lin1_b, h1, R, 2048, 512, 1, 16, RB,
                                                  nullptr, nullptr);
        if (big2)
            gemm256<<<4 * RB2, 512, 0, stream>>>(h1, nullptr, nullptr, nullptr, 0,
                                                 W2T, lin2_b, h2, R, 1024, 2048, 1, 4, RB2);
        else
            gemm_f16<<<8 * RB, 256, 0, stream>>>(h1, nullptr, nullptr, nullptr, 0,
                                                 W2T, lin2_b, h2, R, 1024, 2048, 1, 8, RB,
                                                 nullptr, nullptr);
        // lin3 with fused lin4: atomics into out (fp32)
        gemm_f16<<<4 * RB, 256, 0, stream>>>(h2, nullptr, nullptr, nullptr, rb,
                                             W3T, lin3_b, nullptr, R, 512, 1024, 1, 4, RB,
                                             lin4_W, out);
    }
}